// Round 1
// baseline (6864.655 us; speedup 1.0000x reference)
//
#include <hip/hip_runtime.h>

// Problem constants (fixed by setup_inputs)
#define NIMG 128
#define NTXT 128
#define RDIM 48     // regions per image
#define LWRD 64     // max words per text
#define DDIM 1024   // feature dim
#define LAMB 20.0f
#define FEPS 1e-8f

// ws layout (floats): [0,6144) invq  1/(||img_q[n,r]||+eps)
//                     [6144,12288) vnorm ||img_v[n,r]||
//                     [12288,20480) invk 1/(||txt_k[t,l]||+eps)
//                     [20480,28672) tvn ||txt_v[t,l]||
#define WS_INVQ 0
#define WS_VN   6144
#define WS_INVK 12288
#define WS_TVN  20480

__global__ __launch_bounds__(256, 2)
void prep_norms(const float* __restrict__ imq, const float* __restrict__ imv,
                const float* __restrict__ txk, const float* __restrict__ txv,
                float* __restrict__ ws) {
    int vid = blockIdx.x * 4 + (threadIdx.x >> 6);
    int lane = threadIdx.x & 63;
    const float* src;
    if (vid < 6144)       src = imq + (size_t)vid * 1024;
    else if (vid < 12288) src = imv + (size_t)(vid - 6144) * 1024;
    else if (vid < 20480) src = txk + (size_t)(vid - 12288) * 1024;
    else                  src = txv + (size_t)(vid - 20480) * 1024;
    const float4* s4 = (const float4*)src;
    float acc = 0.f;
#pragma unroll
    for (int j = 0; j < 4; ++j) {
        float4 v = s4[lane + 64 * j];
        acc += v.x * v.x + v.y * v.y + v.z * v.z + v.w * v.w;
    }
#pragma unroll
    for (int off = 32; off; off >>= 1) acc += __shfl_down(acc, off, 64);
    if (lane == 0) {
        float nrm = sqrtf(acc);
        // segments alternate inv(+eps) / raw-norm; index == vid in all four
        if (vid < 6144)       ws[vid] = 1.f / (nrm + FEPS);
        else if (vid < 12288) ws[vid] = nrm;
        else if (vid < 20480) ws[vid] = 1.f / (nrm + FEPS);
        else                  ws[vid] = nrm;
    }
}

// One block per (n = blockIdx.x, t = blockIdx.y): x-fastest dispatch means
// concurrent blocks share one text's tk/tv (hot in L2).
__global__ __launch_bounds__(256, 2)
void loss_main(const float* __restrict__ imq, const float* __restrict__ imv,
               const float* __restrict__ txk, const float* __restrict__ txv,
               const int* __restrict__ tlen, const float* __restrict__ ws,
               float* __restrict__ out) {
    const int n = blockIdx.x, t = blockIdx.y;
    const int tid = threadIdx.x;
    const int tx = tid & 15, ty = tid >> 4;

    // Phase A: sX = tk rows [l][k] (stride 68), sY = qn rows [r][k] (stride 68)
    // Phase B: sX = tv_T [k][l] (stride 68), sY = v_T [k][r] (stride 52)
    __shared__ float sX[64 * 68];
    __shared__ float sY[64 * 68];
    __shared__ float sP[64 * 49];    // leaky_relu(S) [l][r]
    __shared__ float sA1[48 * 68];   // i2t attention [r][l]
    __shared__ float sA2[64 * 52];   // t2i attention [l][r]
    __shared__ float sNl[64], sNr[48];
    __shared__ float sInvK[64], sTvN[64], sInvQ[48], sVN[48];
    __shared__ float sD1[48], sS1[48], sD2[64], sS2[64];

    const int nw = tlen[t];
    const float nwf = (float)nw;
    if (tid < 64) {
        sInvK[tid] = ws[WS_INVK + t * 64 + tid];
        sTvN[tid]  = ws[WS_TVN + t * 64 + tid];
    } else if (tid < 112) {
        int r = tid - 64;
        sInvQ[r] = ws[WS_INVQ + n * 48 + r];
        sVN[r]   = ws[WS_VN + n * 48 + r];
    }
    __syncthreads();

    const float* tkb = txk + (size_t)t * (LWRD * DDIM);
    const float* tvb = txv + (size_t)t * (LWRD * DDIM);
    const float* qnb = imq + (size_t)n * (RDIM * DDIM);
    const float* ivb = imv + (size_t)n * (RDIM * DDIM);

    // ---------------- Phase A: S[l][r] = tk_hat[l] . q_hat[r] ----------------
    float acc[4][3];
#pragma unroll
    for (int i = 0; i < 4; ++i)
#pragma unroll
        for (int j = 0; j < 3; ++j) acc[i][j] = 0.f;

    for (int kc = 0; kc < 16; ++kc) {
        const int k0 = kc * 64;
        {   // stage tk (scaled, padded rows zeroed)
            int la = tid >> 2, c4 = tid & 3;
            float sc = (la < nw) ? sInvK[la] : 0.f;
            const float4* g = (const float4*)(tkb + (size_t)la * DDIM + k0);
#pragma unroll
            for (int s = 0; s < 4; ++s) {
                float4 v = g[c4 + 4 * s];
                v.x *= sc; v.y *= sc; v.z *= sc; v.w *= sc;
                *(float4*)&sX[la * 68 + 4 * (c4 + 4 * s)] = v;
            }
        }
        if (tid < 192) {   // stage qn (scaled)
            int ra = tid >> 2, c4 = tid & 3;
            float sc = sInvQ[ra];
            const float4* g = (const float4*)(qnb + (size_t)ra * DDIM + k0);
#pragma unroll
            for (int s = 0; s < 4; ++s) {
                float4 v = g[c4 + 4 * s];
                v.x *= sc; v.y *= sc; v.z *= sc; v.w *= sc;
                *(float4*)&sY[ra * 68 + 4 * (c4 + 4 * s)] = v;
            }
        }
        __syncthreads();
#pragma unroll 4
        for (int k4 = 0; k4 < 16; ++k4) {
            float4 a[4], b[3];
#pragma unroll
            for (int i = 0; i < 4; ++i) a[i] = *(const float4*)&sX[(ty + 16 * i) * 68 + 4 * k4];
#pragma unroll
            for (int j = 0; j < 3; ++j) b[j] = *(const float4*)&sY[(tx + 16 * j) * 68 + 4 * k4];
#pragma unroll
            for (int i = 0; i < 4; ++i)
#pragma unroll
                for (int j = 0; j < 3; ++j)
                    acc[i][j] += a[i].x * b[j].x + a[i].y * b[j].y +
                                 a[i].z * b[j].z + a[i].w * b[j].w;
        }
        __syncthreads();
    }
    // leaky_relu + store S to LDS (padded l rows are exactly 0)
#pragma unroll
    for (int i = 0; i < 4; ++i)
#pragma unroll
        for (int j = 0; j < 3; ++j) {
            float v = acc[i][j];
            v = (v > 0.f) ? v : 0.1f * v;
            sP[(ty + 16 * i) * 49 + (tx + 16 * j)] = v;
        }
    __syncthreads();

    // ---------------- norms over r (per l) and over l (per r) ----------------
    if (tid < 64) {
        float s = 0.f;
#pragma unroll 4
        for (int r = 0; r < 48; ++r) { float v = sP[tid * 49 + r]; s += v * v; }
        sNl[tid] = sqrtf(s) + FEPS;
    } else if (tid < 112) {
        int r = tid - 64;
        float s = 0.f;
#pragma unroll 4
        for (int l = 0; l < 64; ++l) { float v = sP[l * 49 + r]; s += v * v; }
        sNr[r] = sqrtf(s) + FEPS;
    }
    __syncthreads();

    // ------------- softmax + focal renorm (wave0: i2t, wave1: t2i) -----------
    if (tid < 48) {
        const int r = tid;
        float mx = -1e30f;
        for (int l = 0; l < nw; ++l) {
            float v = LAMB * (sP[l * 49 + r] / sNl[l]);
            sA1[r * 68 + l] = v;
            mx = fmaxf(mx, v);
        }
        float se = 0.f;
        for (int l = 0; l < nw; ++l) {
            float e = __expf(sA1[r * 68 + l] - mx);
            sA1[r * 68 + l] = e; se += e;
        }
        float suma = 0.f;
        for (int l = 0; l < nw; ++l) {
            float a = sA1[r * 68 + l] / se;
            sA1[r * 68 + l] = a; suma += a;
        }
        float s2 = 0.f;
        for (int l = 0; l < nw; ++l) {
            float a = sA1[r * 68 + l];
            if (a * nwf - suma > 0.f) s2 += a;
        }
        float ri = (s2 > 0.f) ? 1.f / s2 : 1.f;
        for (int l = 0; l < 64; ++l) {
            float a = (l < nw) ? sA1[r * 68 + l] : 0.f;
            sA1[r * 68 + l] = (l < nw && (a * nwf - suma > 0.f)) ? a * ri : 0.f;
        }
    } else if (tid < 128) {
        const int l = tid - 64;
        if (l < nw) {
            float mx = -1e30f;
            for (int r = 0; r < 48; ++r) {
                float v = LAMB * (sP[l * 49 + r] / sNr[r]);
                sA2[l * 52 + r] = v;
                mx = fmaxf(mx, v);
            }
            float se = 0.f;
            for (int r = 0; r < 48; ++r) {
                float e = __expf(sA2[l * 52 + r] - mx);
                sA2[l * 52 + r] = e; se += e;
            }
            float suma = 0.f;
            for (int r = 0; r < 48; ++r) {
                float a = sA2[l * 52 + r] / se;
                sA2[l * 52 + r] = a; suma += a;
            }
            float s2 = 0.f;
            for (int r = 0; r < 48; ++r) {
                float a = sA2[l * 52 + r];
                if (a * 48.0f - suma > 0.f) s2 += a;
            }
            float ri = (s2 > 0.f) ? 1.f / s2 : 1.f;
            for (int r = 0; r < 48; ++r) {
                float a = sA2[l * 52 + r];
                sA2[l * 52 + r] = (a * 48.0f - suma > 0.f) ? a * ri : 0.f;
            }
        } else {
            for (int r = 0; r < 48; ++r) sA2[l * 52 + r] = 0.f;
        }
    } else {
        for (int idx = tid - 128; idx < 224; idx += 128) {
            if (idx < 48)       sD1[idx] = 0.f;
            else if (idx < 96)  sS1[idx - 48] = 0.f;
            else if (idx < 160) sD2[idx - 96] = 0.f;
            else                sS2[idx - 160] = 0.f;
        }
    }
    __syncthreads();

    // --------- Phase B: W1 = A1@tv, W2 = A2@v, fused cosine partials ---------
    float d1[3] = {0, 0, 0}, s1[3] = {0, 0, 0};
    float d2[4] = {0, 0, 0, 0}, s2a[4] = {0, 0, 0, 0};

    for (int kc = 0; kc < 16; ++kc) {
        const int k0 = kc * 64;
        {   // stage tv transposed: sX[kloc][l], wave-uniform k per store
            int w = tid >> 6, lane = tid & 63;
            const float4* g = (const float4*)(tvb + (size_t)lane * DDIM + k0);
#pragma unroll
            for (int s = 0; s < 4; ++s) {
                float4 v = g[4 * w + s];
                int kl = 16 * w + 4 * s;
                sX[(kl + 0) * 68 + lane] = v.x;
                sX[(kl + 1) * 68 + lane] = v.y;
                sX[(kl + 2) * 68 + lane] = v.z;
                sX[(kl + 3) * 68 + lane] = v.w;
            }
        }
        {   // stage img_v transposed: sY[kloc][r]
            int w = tid >> 6, lane = tid & 63;
            if (lane < 48) {
                const float4* g = (const float4*)(ivb + (size_t)lane * DDIM + k0);
#pragma unroll
                for (int p = 0; p < 4; ++p) {
                    float4 v = g[4 * w + p];
                    int kl = 16 * w + 4 * p;
                    sY[(kl + 0) * 52 + lane] = v.x;
                    sY[(kl + 1) * 52 + lane] = v.y;
                    sY[(kl + 2) * 52 + lane] = v.z;
                    sY[(kl + 3) * 52 + lane] = v.w;
                }
            }
        }
        __syncthreads();

        float w1[4][3], w2[4][4];
#pragma unroll
        for (int i = 0; i < 4; ++i) {
#pragma unroll
            for (int j = 0; j < 3; ++j) w1[i][j] = 0.f;
#pragma unroll
            for (int m = 0; m < 4; ++m) w2[i][m] = 0.f;
        }
        // W1[r=tx+16j][kk=ty+16i] = sum_l A1[r][l]*tv[l][kk]
#pragma unroll 2
        for (int l4 = 0; l4 < 16; ++l4) {
            float4 aj[3], ti[4];
#pragma unroll
            for (int j = 0; j < 3; ++j) aj[j] = *(const float4*)&sA1[(tx + 16 * j) * 68 + 4 * l4];
#pragma unroll
            for (int i = 0; i < 4; ++i) ti[i] = *(const float4*)&sX[(ty + 16 * i) * 68 + 4 * l4];
#pragma unroll
            for (int i = 0; i < 4; ++i)
#pragma unroll
                for (int j = 0; j < 3; ++j)
                    w1[i][j] += aj[j].x * ti[i].x + aj[j].y * ti[i].y +
                                aj[j].z * ti[i].z + aj[j].w * ti[i].w;
        }
        // W2[l=ty+16i][kk=tx+16m] = sum_r A2[l][r]*v[r][kk]
#pragma unroll 2
        for (int r4 = 0; r4 < 12; ++r4) {
            float4 ai[4], vm[4];
#pragma unroll
            for (int i = 0; i < 4; ++i) ai[i] = *(const float4*)&sA2[(ty + 16 * i) * 52 + 4 * r4];
#pragma unroll
            for (int m = 0; m < 4; ++m) vm[m] = *(const float4*)&sY[(tx + 16 * m) * 52 + 4 * r4];
#pragma unroll
            for (int i = 0; i < 4; ++i)
#pragma unroll
                for (int m = 0; m < 4; ++m)
                    w2[i][m] += ai[i].x * vm[m].x + ai[i].y * vm[m].y +
                                ai[i].z * vm[m].z + ai[i].w * vm[m].w;
        }
        // fused cosine partials (wei matrices never touch global memory)
#pragma unroll
        for (int i = 0; i < 4; ++i)
#pragma unroll
            for (int j = 0; j < 3; ++j) {
                float vv = sY[(ty + 16 * i) * 52 + (tx + 16 * j)];
                d1[j] += w1[i][j] * vv;
                s1[j] += w1[i][j] * w1[i][j];
            }
#pragma unroll
        for (int i = 0; i < 4; ++i)
#pragma unroll
            for (int m = 0; m < 4; ++m) {
                float tvv = sX[(tx + 16 * m) * 68 + (ty + 16 * i)];
                d2[i] += w2[i][m] * tvv;
                s2a[i] += w2[i][m] * w2[i][m];
            }
        __syncthreads();
    }

#pragma unroll
    for (int j = 0; j < 3; ++j) {
        atomicAdd(&sD1[tx + 16 * j], d1[j]);
        atomicAdd(&sS1[tx + 16 * j], s1[j]);
    }
#pragma unroll
    for (int i = 0; i < 4; ++i) {
        atomicAdd(&sD2[ty + 16 * i], d2[i]);
        atomicAdd(&sS2[ty + 16 * i], s2a[i]);
    }
    __syncthreads();

    // cosine epilogue, replicating reference eps semantics exactly:
    // w_hat = w/(||w||+eps); cos = (v.w_hat)/max(||v||*||w_hat||, eps)
    if (tid < 48) {
        int r = tid;
        float wn = sqrtf(sS1[r]);
        float dh = sD1[r] / (wn + FEPS);
        float nh = wn / (wn + FEPS);
        float den = fmaxf(sVN[r] * nh, FEPS);
        sD1[r] = dh / den;
    } else if (tid >= 64 && tid < 128) {
        int l = tid - 64;
        if (l < nw) {
            float wn = sqrtf(sS2[l]);
            float dh = sD2[l] / (wn + FEPS);
            float nh = wn / (wn + FEPS);
            float den = fmaxf(sTvN[l] * nh, FEPS);
            sD2[l] = dh / den;
        }
    }
    __syncthreads();
    if (tid == 0) {
        float s = 0.f;
        for (int r = 0; r < 48; ++r) s += sD1[r];
        out[(size_t)n * NTXT + t] = s / 48.0f;
    } else if (tid == 64) {
        float s = 0.f;
        for (int l = 0; l < nw; ++l) s += sD2[l];
        out[(size_t)(NIMG * NTXT) + (size_t)n * NTXT + t] = s / nwf;
    }
}

extern "C" void kernel_launch(void* const* d_in, const int* in_sizes, int n_in,
                              void* d_out, int out_size, void* d_ws, size_t ws_size,
                              hipStream_t stream) {
    (void)in_sizes; (void)n_in; (void)out_size; (void)ws_size;
    const float* imq = (const float*)d_in[0];
    const float* imv = (const float*)d_in[1];
    const float* txk = (const float*)d_in[2];
    const float* txv = (const float*)d_in[3];
    const int*   tln = (const int*)d_in[4];
    float* out = (float*)d_out;
    float* ws  = (float*)d_ws;   // 28672 floats = 112 KiB

    prep_norms<<<7168, 256, 0, stream>>>(imq, imv, txk, txv, ws);
    dim3 grid(NIMG, NTXT);
    loss_main<<<grid, 256, 0, stream>>>(imq, imv, txk, txv, tln, ws, out);
}

// Round 2
// 1702.070 us; speedup vs baseline: 4.0331x; 4.0331x over previous
//
#include <hip/hip_runtime.h>

#define NIMG 128
#define NTXT 128
#define RDIM 48
#define LWRD 64
#define DDIM 1024
#define LAMB 20.0f
#define FEPS 1e-8f

// ws layout (float offsets)
#define WS_INVQ 0
#define WS_VN   6144
#define WS_INVK 12288
#define WS_TVN  20480
#define WS_H    28672                    // 128 * 64*64
#define WS_VG   552960                   // 128 * 48*48
#define WS_TOTAL_FLOATS 847872
#define WS_TOTAL_BYTES  3391488ull

typedef unsigned int u32;
typedef __attribute__((ext_vector_type(8))) short short8;
typedef __attribute__((ext_vector_type(4))) float f32x4;
typedef __attribute__((ext_vector_type(4))) u32 uintx4;
typedef __attribute__((ext_vector_type(2))) u32 uintx2;

#define MFMA(a,b,c) __builtin_amdgcn_mfma_f32_16x16x32_bf16(a,b,c,0,0,0)

__device__ __forceinline__ u32 f2bf(float x){
    u32 u = __float_as_uint(x);
    return (u + 0x7fffu + ((u >> 16) & 1u)) >> 16;
}
__device__ __forceinline__ float bf2f(u32 h){ return __uint_as_float(h << 16); }
__device__ __forceinline__ u32 packsplit(float x){
    u32 h = f2bf(x);
    u32 l = f2bf(x - bf2f(h));
    return h | (l << 16);
}
__device__ __forceinline__ void unpk(uintx4 a, uintx4 b, short8& hi, short8& lo){
    uintx4 h, l;
    h.x = (a.x & 0xffffu) | (a.y << 16);
    h.y = (a.z & 0xffffu) | (a.w << 16);
    h.z = (b.x & 0xffffu) | (b.y << 16);
    h.w = (b.z & 0xffffu) | (b.w << 16);
    l.x = (a.x >> 16) | (a.y & 0xffff0000u);
    l.y = (a.z >> 16) | (a.w & 0xffff0000u);
    l.z = (b.x >> 16) | (b.y & 0xffff0000u);
    l.w = (b.z >> 16) | (b.w & 0xffff0000u);
    hi = __builtin_bit_cast(short8, h);
    lo = __builtin_bit_cast(short8, l);
}

// staging plane layout (short indices), row stride 40 shorts (80B, bank-clean,
// 16B aligned). hi planes first, lo planes at +LOGAP uniformly.
#define PSTR  40
#define PTKH  0
#define PTVH  2560
#define PQH   5120
#define PVH   8960
#define LOGAP 12800

__device__ __forceinline__ void split_store(short* stg, int idx, float4 x, float sc){
    float a0 = x.x*sc, a1 = x.y*sc, a2 = x.z*sc, a3 = x.w*sc;
    u32 h0=f2bf(a0), h1=f2bf(a1), h2=f2bf(a2), h3=f2bf(a3);
    u32 l0=f2bf(a0-bf2f(h0)), l1=f2bf(a1-bf2f(h1)), l2=f2bf(a2-bf2f(h2)), l3=f2bf(a3-bf2f(h3));
    uintx2 hv; hv.x = h0 | (h1<<16); hv.y = h2 | (h3<<16);
    uintx2 lv; lv.x = l0 | (l1<<16); lv.y = l2 | (l3<<16);
    *(uintx2*)(stg + idx)         = hv;
    *(uintx2*)(stg + idx + LOGAP) = lv;
}

__device__ __forceinline__ short8 frag_ld(const short* stg, int plane, int rb, int m16, int quad){
    return *(const short8*)(stg + plane + (rb + m16) * PSTR + quad * 8);
}

// ---------------------------------------------------------------------------
__global__ __launch_bounds__(256, 2)
void prep_norms(const float* __restrict__ imq, const float* __restrict__ imv,
                const float* __restrict__ txk, const float* __restrict__ txv,
                float* __restrict__ ws) {
    int vid = blockIdx.x * 4 + (threadIdx.x >> 6);
    int lane = threadIdx.x & 63;
    const float* src;
    if (vid < 6144)       src = imq + (size_t)vid * 1024;
    else if (vid < 12288) src = imv + (size_t)(vid - 6144) * 1024;
    else if (vid < 20480) src = txk + (size_t)(vid - 12288) * 1024;
    else                  src = txv + (size_t)(vid - 20480) * 1024;
    const float4* s4 = (const float4*)src;
    float acc = 0.f;
#pragma unroll
    for (int j = 0; j < 4; ++j) {
        float4 v = s4[lane + 64 * j];
        acc += v.x * v.x + v.y * v.y + v.z * v.z + v.w * v.w;
    }
#pragma unroll
    for (int off = 32; off; off >>= 1) acc += __shfl_down(acc, off, 64);
    if (lane == 0) {
        float nrm = sqrtf(acc);
        if (vid < 6144)       ws[vid] = 1.f / (nrm + FEPS);
        else if (vid < 12288) ws[vid] = nrm;
        else if (vid < 20480) ws[vid] = 1.f / (nrm + FEPS);
        else                  ws[vid] = nrm;
    }
}

// ---------------------------------------------------------------------------
// Gram matrices: H[t] = tv tv^T (masked), Vg[n] = v v^T.  fp32 vector.
template <int TS>
__device__ __forceinline__ void gram_body(const float* __restrict__ src,
                                          float* __restrict__ dst, int nw, float* sT){
    const int NR = TS * 16;
    int ar = threadIdx.x >> 4, ac = threadIdx.x & 15;
    float acc[TS][TS];
#pragma unroll
    for (int i = 0; i < TS; ++i)
#pragma unroll
        for (int j = 0; j < TS; ++j) acc[i][j] = 0.f;
    for (int kc = 0; kc < 8; ++kc) {
        int k0 = kc * 128;
        for (int jid = threadIdx.x; jid < NR * 32; jid += 256) {
            int row = jid >> 5, c4 = jid & 31;
            float4 x = *(const float4*)(src + row * 1024 + k0 + c4 * 4);
            float sc = (row < nw) ? 1.f : 0.f;
            x.x *= sc; x.y *= sc; x.z *= sc; x.w *= sc;
            *(float4*)&sT[row * 132 + c4 * 4] = x;
        }
        __syncthreads();
#pragma unroll 4
        for (int k4 = 0; k4 < 32; ++k4) {
            float4 av[TS], bv[TS];
#pragma unroll
            for (int i = 0; i < TS; ++i) av[i] = *(const float4*)&sT[(TS*ar + i) * 132 + k4 * 4];
#pragma unroll
            for (int j = 0; j < TS; ++j) bv[j] = *(const float4*)&sT[(TS*ac + j) * 132 + k4 * 4];
#pragma unroll
            for (int i = 0; i < TS; ++i)
#pragma unroll
                for (int j = 0; j < TS; ++j)
                    acc[i][j] += av[i].x*bv[j].x + av[i].y*bv[j].y + av[i].z*bv[j].z + av[i].w*bv[j].w;
        }
        __syncthreads();
    }
#pragma unroll
    for (int i = 0; i < TS; ++i)
#pragma unroll
        for (int j = 0; j < TS; ++j)
            dst[(TS*ar + i) * NR + TS*ac + j] = acc[i][j];
}

__global__ __launch_bounds__(256, 2)
void gram_kernel(const float* __restrict__ txv, const float* __restrict__ imv,
                 const int* __restrict__ tlen, float* __restrict__ ws){
    __shared__ __align__(16) float sT[64 * 132];
    int b = blockIdx.x;
    if (b < 128) {
        gram_body<4>(txv + (size_t)b * 65536, ws + WS_H + (size_t)b * 4096, tlen[b], sT);
    } else {
        int n = b - 128;
        gram_body<3>(imv + (size_t)n * 49152, ws + WS_VG + (size_t)n * 2304, 48, sT);
    }
}

// ---------------------------------------------------------------------------
// Main fused kernel: one block = (t, image pair n0,n0+1). 4 waves.
__global__ __launch_bounds__(256, 2)
void loss_mfma(const float* __restrict__ imq, const float* __restrict__ imv,
               const float* __restrict__ txk, const float* __restrict__ txv,
               const int* __restrict__ tlen, const float* __restrict__ ws,
               float* __restrict__ out) {
    const int npair = blockIdx.x;
    const int t     = blockIdx.y;
    const int n0    = npair * 2;
    const int tid   = threadIdx.x;
    const int lane  = tid & 63;
    const int w     = tid >> 6;
    const int nl    = w >> 1;      // local image 0/1
    const int hh    = w & 1;       // row (l) half
    const int quad  = lane >> 4;
    const int m16   = lane & 15;

    // LDS: 19904 floats = 79,616 B
    __shared__ __align__(16) float Sm[19904];
    short* stage = (short*)Sm;                  // 25,600 shorts (region 1)
    u32*   A1w   = (u32*)Sm;                    // [2][48][68] aliases stage
    u32*   A2w   = ((u32*)Sm) + 6528;           // [2][64][48]
    float* P     = Sm + 12800;                  // [2][64][49]  (region 2)
    u32*   HVw   = (u32*)(Sm + 12800);          // H[64][68] then Vg[2][48][52]
    float* sInvK = Sm + 19072;                  // 64
    float* sInvQ = sInvK + 64;                  // 96
    float* sNl   = sInvQ + 96;                  // 128 [2][64]
    float* sNr   = sNl + 128;                   // 96  [2][48]
    float* sD1   = sNr + 96;                    // 96
    float* sS1   = sD1 + 96;                    // 96
    float* sD2   = sS1 + 96;                    // 128
    float* sS2   = sD2 + 128;                   // 128

    const int nw = tlen[t];
    const float nwf = (float)nw;
    if (tid < 64) sInvK[tid] = ws[WS_INVK + t * 64 + tid];
    else if (tid < 160) {
        int i = tid - 64; int nn = i >= 48; int r = i - 48 * nn;
        sInvQ[i] = ws[WS_INVQ + (n0 + nn) * 48 + r];
    }
    __syncthreads();

    const float* tkb = txk + (size_t)t * 65536;
    const float* tvb = txv + (size_t)t * 65536;
    const float* qb0 = imq + (size_t)n0 * 49152;   // rows rr in [0,96) are contiguous
    const float* vb0 = imv + (size_t)n0 * 49152;

    // ---- per-thread staging job descriptors (10 float4 jobs / chunk) ----
    const float* sp[10]; int di[10]; float scl[10];
#pragma unroll
    for (int it = 0; it < 10; ++it) {
        int jid = tid + 256 * it;
        const float* s; int plane; int row, c4; float sc;
        if (it < 2) {
            row = jid >> 3; c4 = jid & 7;
            s = tkb + row * 1024 + c4 * 4;
            sc = (row < nw) ? sInvK[row] : 0.f;
            plane = PTKH;
        } else if (it < 4) {
            int j2 = jid - 512; row = j2 >> 3; c4 = j2 & 7;
            s = tvb + row * 1024 + c4 * 4;
            sc = (row < nw) ? 1.f : 0.f;
            plane = PTVH;
        } else if (it < 7) {
            int j2 = jid - 1024; row = j2 >> 3; c4 = j2 & 7;
            s = qb0 + row * 1024 + c4 * 4;
            sc = sInvQ[row];
            plane = PQH;
        } else {
            int j2 = jid - 1792; row = j2 >> 3; c4 = j2 & 7;
            s = vb0 + row * 1024 + c4 * 4;
            sc = 1.f;
            plane = PVH;
        }
        sp[it] = s; di[it] = plane + row * PSTR + c4 * 4; scl[it] = sc;
    }

    // ---- K-loop: S = khat . qhat^T and G = tv . v^T (split-bf16 MFMA) ----
    f32x4 accS[2][3], accG[2][3];
    f32x4 zf = {0.f, 0.f, 0.f, 0.f};
#pragma unroll
    for (int i = 0; i < 2; ++i)
#pragma unroll
        for (int j = 0; j < 3; ++j) { accS[i][j] = zf; accG[i][j] = zf; }

    float4 pf[10];
#pragma unroll
    for (int it = 0; it < 10; ++it) pf[it] = *(const float4*)(sp[it]);

    for (int kc = 0; kc < 32; ++kc) {
#pragma unroll
        for (int it = 0; it < 10; ++it) split_store(stage, di[it], pf[it], scl[it]);
        __syncthreads();
        if (kc < 31) {
            const int ko = (kc + 1) * 32;
#pragma unroll
            for (int it = 0; it < 10; ++it) pf[it] = *(const float4*)(sp[it] + ko);
        }
        short8 akh[2], akl[2], ath[2], atl[2];
#pragma unroll
        for (int i = 0; i < 2; ++i) {
            int rb = 32 * hh + 16 * i;
            akh[i] = frag_ld(stage, PTKH,         rb, m16, quad);
            akl[i] = frag_ld(stage, PTKH + LOGAP, rb, m16, quad);
            ath[i] = frag_ld(stage, PTVH,         rb, m16, quad);
            atl[i] = frag_ld(stage, PTVH + LOGAP, rb, m16, quad);
        }
        short8 bqh[3], bql[3], bvh[3], bvl[3];
#pragma unroll
        for (int j = 0; j < 3; ++j) {
            int rb = nl * 48 + 16 * j;
            bqh[j] = frag_ld(stage, PQH,         rb, m16, quad);
            bql[j] = frag_ld(stage, PQH + LOGAP, rb, m16, quad);
            bvh[j] = frag_ld(stage, PVH,         rb, m16, quad);
            bvl[j] = frag_ld(stage, PVH + LOGAP, rb, m16, quad);
        }
#pragma unroll
        for (int i = 0; i < 2; ++i)
#pragma unroll
            for (int j = 0; j < 3; ++j) {
                accS[i][j] = MFMA(akh[i], bqh[j], accS[i][j]);
                accS[i][j] = MFMA(akh[i], bql[j], accS[i][j]);
                accS[i][j] = MFMA(akl[i], bqh[j], accS[i][j]);
                accG[i][j] = MFMA(ath[i], bvh[j], accG[i][j]);
                accG[i][j] = MFMA(ath[i], bvl[j], accG[i][j]);
                accG[i][j] = MFMA(atl[i], bvh[j], accG[i][j]);
            }
        __syncthreads();
    }

    // ---- P = leaky_relu(S) to LDS (C/D layout: l = 32h+16i+quad*4+v, r = 16j+m16)
#pragma unroll
    for (int i = 0; i < 2; ++i)
#pragma unroll
        for (int j = 0; j < 3; ++j)
#pragma unroll
            for (int v = 0; v < 4; ++v) {
                int l = 32 * hh + 16 * i + quad * 4 + v;
                int r = 16 * j + m16;
                float x = accS[i][j][v];
                P[nl * 3136 + l * 49 + r] = (x > 0.f) ? x : 0.1f * x;
            }
    __syncthreads();

    // ---- norms + zero accumulators ----
    if (tid < 128) {
        int n = tid >> 6, l = tid & 63;
        float s = 0.f;
#pragma unroll 4
        for (int r = 0; r < 48; ++r) { float x = P[n*3136 + l*49 + r]; s += x * x; }
        sNl[n * 64 + l] = sqrtf(s) + FEPS;
    } else if (tid < 224) {
        int i = tid - 128; int n = i >= 48; int r = i - 48 * n;
        float s = 0.f;
#pragma unroll 4
        for (int l = 0; l < 64; ++l) { float x = P[n*3136 + l*49 + r]; s += x * x; }
        sNr[n * 48 + r] = sqrtf(s) + FEPS;
    } else {
        for (int k = tid - 224; k < 448; k += 32) sD1[k] = 0.f;
    }
    __syncthreads();

    // ---- softmax + focal, register resident; A2 on tids 0..127, A1 on 128..223
    if (tid < 128) {
        int n = tid >> 6, l = tid & 63;
        u32* row = A2w + n * 3072 + l * 48;
        if (l < nw) {
            float a[48]; float mx = -1e30f;
            const float* Pr = P + n * 3136 + l * 49;
#pragma unroll
            for (int r = 0; r < 48; ++r) {
                float x = LAMB * Pr[r] / sNr[n * 48 + r];
                a[r] = x; mx = fmaxf(mx, x);
            }
            float se = 0.f;
#pragma unroll
            for (int r = 0; r < 48; ++r) { float e = __expf(a[r] - mx); a[r] = e; se += e; }
            float suma = 0.f;
#pragma unroll
            for (int r = 0; r < 48; ++r) { float x = a[r] / se; a[r] = x; suma += x; }
            float s2 = 0.f;
#pragma unroll
            for (int r = 0; r < 48; ++r) if (a[r] * 48.f - suma > 0.f) s2 += a[r];
            float ri = (s2 > 0.f) ? 1.f / s2 : 1.f;
#pragma unroll
            for (int r = 0; r < 48; ++r) {
                float x = (a[r] * 48.f - suma > 0.f) ? a[r] * ri : 0.f;
                row[r] = packsplit(x);
            }
        } else {
#pragma unroll
            for (int r = 0; r < 48; ++r) row[r] = 0u;
        }
    } else if (tid < 224) {
        int i = tid - 128; int n = i >= 48; int r = i - 48 * n;
        float a[64]; float mx = -1e30f;
#pragma unroll
        for (int l = 0; l < 64; ++l) {
            float x = (l < nw) ? (LAMB * P[n*3136 + l*49 + r] / sNl[n * 64 + l]) : -1e30f;
            a[l] = x; mx = fmaxf(mx, x);
        }
        float se = 0.f;
#pragma unroll
        for (int l = 0; l < 64; ++l) { float e = __expf(a[l] - mx); a[l] = e; se += e; }
        float suma = 0.f;
#pragma unroll
        for (int l = 0; l < 64; ++l) { float x = a[l] / se; a[l] = x; suma += x; }
        float s2 = 0.f;
#pragma unroll
        for (int l = 0; l < 64; ++l) if (a[l] * nwf - suma > 0.f) s2 += a[l];
        float ri = (s2 > 0.f) ? 1.f / s2 : 1.f;
        u32* row = A1w + n * 3264 + r * 68;
#pragma unroll
        for (int l = 0; l < 64; ++l) {
            float x = (a[l] * nwf - suma > 0.f) ? a[l] * ri : 0.f;
            row[l] = packsplit(x);
        }
    }
    __syncthreads();

    // ---- stage H (packed split) over P ----
    {
        const float* Hg = ws + WS_H + (size_t)t * 4096;
        for (int jid = tid; jid < 1024; jid += 256) {
            int row = jid >> 4, c4 = jid & 15;
            float4 x = *(const float4*)(Hg + row * 64 + c4 * 4);
            uintx4 p; p.x = packsplit(x.x); p.y = packsplit(x.y);
            p.z = packsplit(x.z); p.w = packsplit(x.w);
            *(uintx4*)&HVw[row * 68 + c4 * 4] = p;
        }
    }
    __syncthreads();

    // ---- Y = H @ A1^T  (per n); s1/d1 reduction ----
    f32x4 accY[2][3];
#pragma unroll
    for (int i = 0; i < 2; ++i)
#pragma unroll
        for (int j = 0; j < 3; ++j) accY[i][j] = zf;
#pragma unroll
    for (int ks = 0; ks < 2; ++ks) {
        int kb = ks * 32 + quad * 8;
        short8 Ah[2], Al[2];
#pragma unroll
        for (int i = 0; i < 2; ++i) {
            int row = 32 * hh + 16 * i + m16;
            uintx4 wa = *(const uintx4*)&HVw[row * 68 + kb];
            uintx4 wb = *(const uintx4*)&HVw[row * 68 + kb + 4];
            unpk(wa, wb, Ah[i], Al[i]);
        }
        short8 Bh[3], Bl[3];
#pragma unroll
        for (int j = 0; j < 3; ++j) {
            int base = nl * 3264 + (16 * j + m16) * 68 + kb;
            uintx4 wa = *(const uintx4*)&A1w[base];
            uintx4 wb = *(const uintx4*)&A1w[base + 4];
            unpk(wa, wb, Bh[j], Bl[j]);
        }
#pragma unroll
        for (int i = 0; i < 2; ++i)
#pragma unroll
            for (int j = 0; j < 3; ++j) {
                accY[i][j] = MFMA(Ah[i], Bh[j], accY[i][j]);
                accY[i][j] = MFMA(Ah[i], Bl[j], accY[i][j]);
                accY[i][j] = MFMA(Al[i], Bh[j], accY[i][j]);
            }
    }
    {
        float td[3] = {0.f, 0.f, 0.f}, ts[3] = {0.f, 0.f, 0.f};
#pragma unroll
        for (int i = 0; i < 2; ++i)
#pragma unroll
            for (int v = 0; v < 4; ++v) {
                int l = 32 * hh + 16 * i + quad * 4 + v;
#pragma unroll
                for (int j = 0; j < 3; ++j) {
                    u32 wv = A1w[nl * 3264 + (16 * j + m16) * 68 + l];
                    float av = bf2f(wv & 0xffffu) + bf2f(wv >> 16);
                    td[j] += av * accG[i][j][v];
                    ts[j] += av * accY[i][j][v];
                }
            }
#pragma unroll
        for (int j = 0; j < 3; ++j) {
            float d = td[j]; d += __shfl_xor(d, 16, 64); d += __shfl_xor(d, 32, 64);
            float s = ts[j]; s += __shfl_xor(s, 16, 64); s += __shfl_xor(s, 32, 64);
            if (quad == 0) {
                atomicAdd(&sD1[nl * 48 + 16 * j + m16], d);
                atomicAdd(&sS1[nl * 48 + 16 * j + m16], s);
            }
        }
    }
    __syncthreads();

    // ---- stage Vg (both images) over H ----
    {
        const float* Vgg = ws + WS_VG + (size_t)n0 * 2304;
        for (int jid = tid; jid < 1152; jid += 256) {
            int nn = jid >= 576; int j2 = jid - 576 * nn;
            int row = j2 / 12, c4 = j2 % 12;
            float4 x = *(const float4*)(Vgg + nn * 2304 + row * 48 + c4 * 4);
            uintx4 p; p.x = packsplit(x.x); p.y = packsplit(x.y);
            p.z = packsplit(x.z); p.w = packsplit(x.w);
            *(uintx4*)&HVw[nn * 2496 + row * 52 + c4 * 4] = p;
        }
    }
    __syncthreads();

    // ---- Y2 = Vg @ A2^T (per n, K=48 via quad-masked second kstep); s2/d2 ----
    f32x4 accY2[3][2];
#pragma unroll
    for (int i = 0; i < 3; ++i)
#pragma unroll
        for (int j = 0; j < 2; ++j) accY2[i][j] = zf;
    const u32* VgW = HVw + nl * 2496;
#pragma unroll
    for (int ks = 0; ks < 2; ++ks) {
        const bool dead = (ks == 1) && (quad >= 2);
        const int kb = (ks == 0) ? quad * 8 : 32 + (quad & 1) * 8;
        short8 Ah2[3], Al2[3];
#pragma unroll
        for (int i = 0; i < 3; ++i) {
            uintx4 wa = {0,0,0,0}, wb = {0,0,0,0};
            if (!dead) {
                int row = 16 * i + m16;
                wa = *(const uintx4*)&VgW[row * 52 + kb];
                wb = *(const uintx4*)&VgW[row * 52 + kb + 4];
            }
            unpk(wa, wb, Ah2[i], Al2[i]);
        }
        short8 Bh2[2], Bl2[2];
#pragma unroll
        for (int j = 0; j < 2; ++j) {
            uintx4 wa = {0,0,0,0}, wb = {0,0,0,0};
            if (!dead) {
                int l = 32 * hh + 16 * j + m16;
                wa = *(const uintx4*)&A2w[nl * 3072 + l * 48 + kb];
                wb = *(const uintx4*)&A2w[nl * 3072 + l * 48 + kb + 4];
            }
            unpk(wa, wb, Bh2[j], Bl2[j]);
        }
#pragma unroll
        for (int i = 0; i < 3; ++i)
#pragma unroll
            for (int j = 0; j < 2; ++j) {
                accY2[i][j] = MFMA(Ah2[i], Bh2[j], accY2[i][j]);
                accY2[i][j] = MFMA(Ah2[i], Bl2[j], accY2[i][j]);
                accY2[i][j] = MFMA(Al2[i], Bh2[j], accY2[i][j]);
            }
    }
    {
        // s2[l] = sum_r A2[l,r] * Y2[r,l]
        float u[2] = {0.f, 0.f};
#pragma unroll
        for (int i = 0; i < 3; ++i)
#pragma unroll
            for (int v = 0; v < 4; ++v) {
                int r = 16 * i + quad * 4 + v;
#pragma unroll
                for (int j = 0; j < 2; ++j) {
                    int l = 32 * hh + 16 * j + m16;
                    u32 wv = A2w[nl * 3072 + l * 48 + r];
                    float av = bf2f(wv & 0xffffu) + bf2f(wv >> 16);
                    u[j] += av * accY2[i][j][v];
                }
            }
#pragma unroll
        for (int j = 0; j < 2; ++j) {
            float s = u[j]; s += __shfl_xor(s, 16, 64); s += __shfl_xor(s, 32, 64);
            if (quad == 0) sS2[nl * 64 + 32 * hh + 16 * j + m16] = s;
        }
        // d2[l] = sum_r A2[l,r] * G[l,r]
        float ud[2][4];
#pragma unroll
        for (int i = 0; i < 2; ++i)
#pragma unroll
            for (int v = 0; v < 4; ++v) ud[i][v] = 0.f;
#pragma unroll
        for (int i = 0; i < 2; ++i)
#pragma unroll
            for (int v = 0; v < 4; ++v) {
                int l = 32 * hh + 16 * i + quad * 4 + v;
#pragma unroll
                for (int j = 0; j < 3; ++j) {
                    u32 wv = A2w[nl * 3072 + l * 48 + (16 * j + m16)];
                    float av = bf2f(wv & 0xffffu) + bf2f(wv >> 16);
                    ud[i][v] += av * accG[i][j][v];
                }
            }
#pragma unroll
        for (int i = 0; i < 2; ++i)
#pragma unroll
            for (int v = 0; v < 4; ++v) {
                float d = ud[i][v];
                d += __shfl_xor(d, 1, 64); d += __shfl_xor(d, 2, 64);
                d += __shfl_xor(d, 4, 64); d += __shfl_xor(d, 8, 64);
                if (m16 == 0) sD2[nl * 64 + 32 * hh + 16 * i + quad * 4 + v] = d;
            }
    }
    __syncthreads();

    // ---- cosine epilogue (reference eps semantics) ----
    if (tid < 96) {
        int n = tid >= 48; int r = tid - 48 * n;
        float wn = sqrtf(sS1[n * 48 + r]);
        float dh = sD1[n * 48 + r] / (wn + FEPS);
        float nh = wn / (wn + FEPS);
        float vn = ws[WS_VN + (n0 + n) * 48 + r];
        sD1[n * 48 + r] = dh / fmaxf(vn * nh, FEPS);
    } else if (tid >= 128) {
        int i = tid - 128; int n = i >> 6, l = i & 63;
        if (l < nw) {
            float wn = sqrtf(sS2[n * 64 + l]);
            float dh = sD2[n * 64 + l] / (wn + FEPS);
            float nh = wn / (wn + FEPS);
            float tn = ws[WS_TVN + t * 64 + l];
            sD2[n * 64 + l] = dh / fmaxf(tn * nh, FEPS);
        }
    }
    __syncthreads();
    if (tid < 2) {
        float s = 0.f;
        for (int r = 0; r < 48; ++r) s += sD1[tid * 48 + r];
        out[(size_t)(n0 + tid) * NTXT + t] = s / 48.f;
    } else if (tid == 64 || tid == 65) {
        int n = tid - 64;
        float s = 0.f;
        for (int l = 0; l < nw; ++l) s += sD2[n * 64 + l];
        out[(size_t)(NIMG * NTXT) + (size_t)(n0 + n) * NTXT + t] = s / nwf;
    }
}

// ---------------------------------------------------------------------------
// Round-1 verified fp32 fallback (used only if ws_size is too small).
__global__ __launch_bounds__(256, 2)
void loss_main(const float* __restrict__ imq, const float* __restrict__ imv,
               const float* __restrict__ txk, const float* __restrict__ txv,
               const int* __restrict__ tlen, const float* __restrict__ ws,
               float* __restrict__ out) {
    const int n = blockIdx.x, t = blockIdx.y;
    const int tid = threadIdx.x;
    const int tx = tid & 15, ty = tid >> 4;
    __shared__ float sX[64 * 68];
    __shared__ float sY[64 * 68];
    __shared__ float sP[64 * 49];
    __shared__ float sA1[48 * 68];
    __shared__ float sA2[64 * 52];
    __shared__ float sNl[64], sNr[48];
    __shared__ float sInvK[64], sTvN[64], sInvQ[48], sVN[48];
    __shared__ float sD1[48], sS1[48], sD2[64], sS2[64];
    const int nw = tlen[t];
    const float nwf = (float)nw;
    if (tid < 64) { sInvK[tid] = ws[WS_INVK + t * 64 + tid]; sTvN[tid] = ws[WS_TVN + t * 64 + tid]; }
    else if (tid < 112) { int r = tid - 64; sInvQ[r] = ws[WS_INVQ + n * 48 + r]; sVN[r] = ws[WS_VN + n * 48 + r]; }
    __syncthreads();
    const float* tkb = txk + (size_t)t * 65536;
    const float* tvb = txv + (size_t)t * 65536;
    const float* qnb = imq + (size_t)n * 49152;
    const float* ivb = imv + (size_t)n * 49152;
    float acc[4][3];
#pragma unroll
    for (int i = 0; i < 4; ++i)
#pragma unroll
        for (int j = 0; j < 3; ++j) acc[i][j] = 0.f;
    for (int kc = 0; kc < 16; ++kc) {
        const int k0 = kc * 64;
        { int la = tid >> 2, c4 = tid & 3;
          float sc = (la < nw) ? sInvK[la] : 0.f;
          const float4* g = (const float4*)(tkb + (size_t)la * DDIM + k0);
#pragma unroll
          for (int s = 0; s < 4; ++s) { float4 v = g[c4 + 4 * s];
            v.x *= sc; v.y *= sc; v.z *= sc; v.w *= sc;
            *(float4*)&sX[la * 68 + 4 * (c4 + 4 * s)] = v; } }
        if (tid < 192) { int ra = tid >> 2, c4 = tid & 3;
          float sc = sInvQ[ra];
          const float4* g = (const float4*)(qnb + (size_t)ra * DDIM + k0);
#pragma unroll
          for (int s = 0; s < 4; ++s) { float4 v = g[c4 + 4 * s];
            v.x *= sc; v.y *= sc; v.z *= sc; v.w *= sc;
            *(float4*)&sY[ra * 68 + 4 * (c4 + 4 * s)] = v; } }
        __syncthreads();
#pragma unroll 4
        for (int k4 = 0; k4 < 16; ++k4) {
            float4 a[4], b[3];
#pragma unroll
            for (int i = 0; i < 4; ++i) a[i] = *(const float4*)&sX[(ty + 16 * i) * 68 + 4 * k4];
#pragma unroll
            for (int j = 0; j < 3; ++j) b[j] = *(const float4*)&sY[(tx + 16 * j) * 68 + 4 * k4];
#pragma unroll
            for (int i = 0; i < 4; ++i)
#pragma unroll
                for (int j = 0; j < 3; ++j)
                    acc[i][j] += a[i].x * b[j].x + a[i].y * b[j].y + a[i].z * b[j].z + a[i].w * b[j].w;
        }
        __syncthreads();
    }
#pragma unroll
    for (int i = 0; i < 4; ++i)
#pragma unroll
        for (int j = 0; j < 3; ++j) {
            float v = acc[i][j];
            v = (v > 0.f) ? v : 0.1f * v;
            sP[(ty + 16 * i) * 49 + (tx + 16 * j)] = v;
        }
    __syncthreads();
    if (tid < 64) { float s = 0.f;
#pragma unroll 4
        for (int r = 0; r < 48; ++r) { float v = sP[tid * 49 + r]; s += v * v; }
        sNl[tid] = sqrtf(s) + FEPS;
    } else if (tid < 112) { int r = tid - 64; float s = 0.f;
#pragma unroll 4
        for (int l = 0; l < 64; ++l) { float v = sP[l * 49 + r]; s += v * v; }
        sNr[r] = sqrtf(s) + FEPS; }
    __syncthreads();
    if (tid < 48) {
        const int r = tid;
        float mx = -1e30f;
        for (int l = 0; l < nw; ++l) { float v = LAMB * (sP[l * 49 + r] / sNl[l]); sA1[r * 68 + l] = v; mx = fmaxf(mx, v); }
        float se = 0.f;
        for (int l = 0; l < nw; ++l) { float e = __expf(sA1[r * 68 + l] - mx); sA1[r * 68 + l] = e; se += e; }
        float suma = 0.f;
        for (int l = 0; l < nw; ++l) { float a = sA1[r * 68 + l] / se; sA1[r * 68 + l] = a; suma += a; }
        float s2 = 0.f;
        for (int l = 0; l < nw; ++l) { float a = sA1[r * 68 + l]; if (a * nwf - suma > 0.f) s2 += a; }
        float ri = (s2 > 0.f) ? 1.f / s2 : 1.f;
        for (int l = 0; l < 64; ++l) {
            float a = (l < nw) ? sA1[r * 68 + l] : 0.f;
            sA1[r * 68 + l] = (l < nw && (a * nwf - suma > 0.f)) ? a * ri : 0.f;
        }
    } else if (tid < 128) {
        const int l = tid - 64;
        if (l < nw) {
            float mx = -1e30f;
            for (int r = 0; r < 48; ++r) { float v = LAMB * (sP[l * 49 + r] / sNr[r]); sA2[l * 52 + r] = v; mx = fmaxf(mx, v); }
            float se = 0.f;
            for (int r = 0; r < 48; ++r) { float e = __expf(sA2[l * 52 + r] - mx); sA2[l * 52 + r] = e; se += e; }
            float suma = 0.f;
            for (int r = 0; r < 48; ++r) { float a = sA2[l * 52 + r] / se; sA2[l * 52 + r] = a; suma += a; }
            float s2 = 0.f;
            for (int r = 0; r < 48; ++r) { float a = sA2[l * 52 + r]; if (a * 48.0f - suma > 0.f) s2 += a; }
            float ri = (s2 > 0.f) ? 1.f / s2 : 1.f;
            for (int r = 0; r < 48; ++r) { float a = sA2[l * 52 + r]; sA2[l * 52 + r] = (a * 48.0f - suma > 0.f) ? a * ri : 0.f; }
        } else { for (int r = 0; r < 48; ++r) sA2[l * 52 + r] = 0.f; }
    } else {
        for (int idx = tid - 128; idx < 224; idx += 128) {
            if (idx < 48) sD1[idx] = 0.f;
            else if (idx < 96) sS1[idx - 48] = 0.f;
            else if (idx < 160) sD2[idx - 96] = 0.f;
            else sS2[idx - 160] = 0.f;
        }
    }
    __syncthreads();
    float d1[3] = {0, 0, 0}, s1[3] = {0, 0, 0};
    float d2[4] = {0, 0, 0, 0}, s2a[4] = {0, 0, 0, 0};
    for (int kc = 0; kc < 16; ++kc) {
        const int k0 = kc * 64;
        { int w2 = tid >> 6, lane = tid & 63;
          const float4* g = (const float4*)(tvb + (size_t)lane * DDIM + k0);
#pragma unroll
          for (int s = 0; s < 4; ++s) { float4 v = g[4 * w2 + s]; int kl = 16 * w2 + 4 * s;
            sX[(kl + 0) * 68 + lane] = v.x; sX[(kl + 1) * 68 + lane] = v.y;
            sX[(kl + 2) * 68 + lane] = v.z; sX[(kl + 3) * 68 + lane] = v.w; } }
        { int w2 = tid >> 6, lane = tid & 63;
          if (lane < 48) {
            const float4* g = (const float4*)(ivb + (size_t)lane * DDIM + k0);
#pragma unroll
            for (int p = 0; p < 4; ++p) { float4 v = g[4 * w2 + p]; int kl = 16 * w2 + 4 * p;
              sY[(kl + 0) * 52 + lane] = v.x; sY[(kl + 1) * 52 + lane] = v.y;
              sY[(kl + 2) * 52 + lane] = v.z; sY[(kl + 3) * 52 + lane] = v.w; } } }
        __syncthreads();
        float w1[4][3], w2m[4][4];
#pragma unroll
        for (int i = 0; i < 4; ++i) {
#pragma unroll
            for (int j = 0; j < 3; ++j) w1[i][j] = 0.f;
#pragma unroll
            for (int m = 0; m < 4; ++m) w2m[i][m] = 0.f;
        }
#pragma unroll 2
        for (int l4 = 0; l4 < 16; ++l4) {
            float4 aj[3], ti[4];
#pragma unroll
            for (int j = 0; j < 3; ++j) aj[j] = *(const float4*)&sA1[(tx + 16 * j) * 68 + 4 * l4];
#pragma unroll
            for (int i = 0; i < 4; ++i) ti[i] = *(const float4*)&sX[(ty + 16 * i) * 68 + 4 * l4];
#pragma unroll
            for (int i = 0; i < 4; ++i)
#pragma unroll
                for (int j = 0; j < 3; ++j)
                    w1[i][j] += aj[j].x * ti[i].x + aj[j].y * ti[i].y + aj[j].z * ti[i].z + aj[j].w * ti[i].w;
        }
#pragma unroll 2
        for (int r4 = 0; r4 < 12; ++r4) {
            float4 ai[4], vm[4];
#pragma unroll
            for (int i = 0; i < 4; ++i) ai[i] = *(const float4*)&sA2[(ty + 16 * i) * 52 + 4 * r4];
#pragma unroll
            for (int m = 0; m < 4; ++m) vm[m] = *(const float4*)&sY[(tx + 16 * m) * 52 + 4 * r4];
#pragma unroll
            for (int i = 0; i < 4; ++i)
#pragma unroll
                for (int m = 0; m < 4; ++m)
                    w2m[i][m] += ai[i].x * vm[m].x + ai[i].y * vm[m].y + ai[i].z * vm[m].z + ai[i].w * vm[m].w;
        }
#pragma unroll
        for (int i = 0; i < 4; ++i)
#pragma unroll
            for (int j = 0; j < 3; ++j) {
                float vv = sY[(ty + 16 * i) * 52 + (tx + 16 * j)];
                d1[j] += w1[i][j] * vv; s1[j] += w1[i][j] * w1[i][j];
            }
#pragma unroll
        for (int i = 0; i < 4; ++i)
#pragma unroll
            for (int m = 0; m < 4; ++m) {
                float tvv = sX[(tx + 16 * m) * 68 + (ty + 16 * i)];
                d2[i] += w2m[i][m] * tvv; s2a[i] += w2m[i][m] * w2m[i][m];
            }
        __syncthreads();
    }
#pragma unroll
    for (int j = 0; j < 3; ++j) { atomicAdd(&sD1[tx + 16 * j], d1[j]); atomicAdd(&sS1[tx + 16 * j], s1[j]); }
#pragma unroll
    for (int i = 0; i < 4; ++i) { atomicAdd(&sD2[ty + 16 * i], d2[i]); atomicAdd(&sS2[ty + 16 * i], s2a[i]); }
    __syncthreads();
    if (tid < 48) {
        int r = tid;
        float wn = sqrtf(sS1[r]);
        float dh = sD1[r] / (wn + FEPS);
        float nh = wn / (wn + FEPS);
        sD1[r] = dh / fmaxf(sVN[r] * nh, FEPS);
    } else if (tid >= 64 && tid < 128) {
        int l = tid - 64;
        if (l < nw) {
            float wn = sqrtf(sS2[l]);
            float dh = sD2[l] / (wn + FEPS);
            float nh = wn / (wn + FEPS);
            sD2[l] = dh / fmaxf(sTvN[l] * nh, FEPS);
        }
    }
    __syncthreads();
    if (tid == 0) {
        float s = 0.f;
        for (int r = 0; r < 48; ++r) s += sD1[r];
        out[(size_t)n * NTXT + t] = s / 48.0f;
    } else if (tid == 64) {
        float s = 0.f;
        for (int l = 0; l < nw; ++l) s += sD2[l];
        out[(size_t)(NIMG * NTXT) + (size_t)n * NTXT + t] = s / nwf;
    }
}

extern "C" void kernel_launch(void* const* d_in, const int* in_sizes, int n_in,
                              void* d_out, int out_size, void* d_ws, size_t ws_size,
                              hipStream_t stream) {
    (void)in_sizes; (void)n_in; (void)out_size;
    const float* imq = (const float*)d_in[0];
    const float* imv = (const float*)d_in[1];
    const float* txk = (const float*)d_in[2];
    const float* txv = (const float*)d_in[3];
    const int*   tln = (const int*)d_in[4];
    float* out = (float*)d_out;
    float* ws  = (float*)d_ws;

    prep_norms<<<7168, 256, 0, stream>>>(imq, imv, txk, txv, ws);
    if (ws_size >= WS_TOTAL_BYTES) {
        gram_kernel<<<256, 256, 0, stream>>>(txv, imv, tln, ws);
        dim3 grid(64, 128);
        loss_mfma<<<grid, 256, 0, stream>>>(imq, imv, txk, txv, tln, ws, out);
    } else {
        dim3 grid(NIMG, NTXT);
        loss_main<<<grid, 256, 0, stream>>>(imq, imv, txk, txv, tln, ws, out);
    }
}

// Round 3
// 1122.710 us; speedup vs baseline: 6.1144x; 1.5160x over previous
//
#include <hip/hip_runtime.h>

#define NIMG 128
#define NTXT 128
#define RDIM 48
#define LWRD 64
#define DDIM 1024
#define LAMB 20.0f
#define FEPS 1e-8f

// ---- ws layout ----
// float offsets (round-2 compatible region):
#define WS_INVQ 0
#define WS_VN   6144
#define WS_INVK 12288
#define WS_TVN  20480
#define WS_H    28672        // fp32 H (mid/fallback path), 524288 floats
#define WS_VG   552960       // fp32 Vg (mid path), 294912 floats
#define WS_MID_BYTES 3391488ull
// big path: packed-split u32 grams + split-bf16 planes
#define WS_HU   847872       // u32 index: H packed-split, 128*4096
#define WS_VGU  1372160      // u32 index: Vg packed-split, 128*2304
// short indices into ws for split planes (chunk-tiled [kc][row][32]):
#define SP_TK   3334144      // per t: hi[32][64][32]=65536 shorts, lo at +65536
#define SP_TV   20111360
#define SP_Q    36888576     // per n: hi[32][48][32]=49152, lo at +49152
#define SP_V    49471488
#define WS_BIG_BYTES 124108800ull

typedef unsigned int u32;
typedef unsigned short u16;
typedef __attribute__((ext_vector_type(8))) short short8;
typedef __attribute__((ext_vector_type(4))) float f32x4;
typedef __attribute__((ext_vector_type(4))) u32 uintx4;
typedef __attribute__((ext_vector_type(2))) u32 uintx2;

#define MFMA(a,b,c) __builtin_amdgcn_mfma_f32_16x16x32_bf16(a,b,c,0,0,0)

__device__ __forceinline__ u32 f2bf(float x){
    u32 u = __float_as_uint(x);
    return (u + 0x7fffu + ((u >> 16) & 1u)) >> 16;
}
__device__ __forceinline__ float bf2f(u32 h){ return __uint_as_float(h << 16); }
__device__ __forceinline__ u32 packsplit(float x){
    u32 h = f2bf(x);
    u32 l = f2bf(x - bf2f(h));
    return h | (l << 16);
}
__device__ __forceinline__ void unpk(uintx4 a, uintx4 b, short8& hi, short8& lo){
    uintx4 h, l;
    h.x = (a.x & 0xffffu) | (a.y << 16);
    h.y = (a.z & 0xffffu) | (a.w << 16);
    h.z = (b.x & 0xffffu) | (b.y << 16);
    h.w = (b.z & 0xffffu) | (b.w << 16);
    l.x = (a.x >> 16) | (a.y & 0xffff0000u);
    l.y = (a.z >> 16) | (a.w & 0xffff0000u);
    l.z = (b.x >> 16) | (b.y & 0xffff0000u);
    l.w = (b.z >> 16) | (b.w & 0xffff0000u);
    hi = __builtin_bit_cast(short8, h);
    lo = __builtin_bit_cast(short8, l);
}

// round-2 fallback staging helpers
#define PSTR  40
#define PTKH  0
#define PTVH  2560
#define PQH   5120
#define PVH   8960
#define LOGAP 12800
__device__ __forceinline__ void split_store(short* stg, int idx, float4 x, float sc){
    float a0 = x.x*sc, a1 = x.y*sc, a2 = x.z*sc, a3 = x.w*sc;
    u32 h0=f2bf(a0), h1=f2bf(a1), h2=f2bf(a2), h3=f2bf(a3);
    u32 l0=f2bf(a0-bf2f(h0)), l1=f2bf(a1-bf2f(h1)), l2=f2bf(a2-bf2f(h2)), l3=f2bf(a3-bf2f(h3));
    uintx2 hv; hv.x = h0 | (h1<<16); hv.y = h2 | (h3<<16);
    uintx2 lv; lv.x = l0 | (l1<<16); lv.y = l2 | (l3<<16);
    *(uintx2*)(stg + idx)         = hv;
    *(uintx2*)(stg + idx + LOGAP) = lv;
}
__device__ __forceinline__ short8 frag_ld(const short* stg, int plane, int rb, int m16, int quad){
    return *(const short8*)(stg + plane + (rb + m16) * PSTR + quad * 8);
}

// ---------------------------------------------------------------------------
__global__ __launch_bounds__(256, 2)
void prep_norms(const float* __restrict__ imq, const float* __restrict__ imv,
                const float* __restrict__ txk, const float* __restrict__ txv,
                float* __restrict__ ws) {
    int vid = blockIdx.x * 4 + (threadIdx.x >> 6);
    int lane = threadIdx.x & 63;
    const float* src;
    if (vid < 6144)       src = imq + (size_t)vid * 1024;
    else if (vid < 12288) src = imv + (size_t)(vid - 6144) * 1024;
    else if (vid < 20480) src = txk + (size_t)(vid - 12288) * 1024;
    else                  src = txv + (size_t)(vid - 20480) * 1024;
    const float4* s4 = (const float4*)src;
    float acc = 0.f;
#pragma unroll
    for (int j = 0; j < 4; ++j) {
        float4 v = s4[lane + 64 * j];
        acc += v.x * v.x + v.y * v.y + v.z * v.z + v.w * v.w;
    }
#pragma unroll
    for (int off = 32; off; off >>= 1) acc += __shfl_down(acc, off, 64);
    if (lane == 0) {
        float nrm = sqrtf(acc);
        if (vid < 6144)       ws[vid] = 1.f / (nrm + FEPS);
        else if (vid < 12288) ws[vid] = nrm;
        else if (vid < 20480) ws[vid] = 1.f / (nrm + FEPS);
        else                  ws[vid] = nrm;
    }
}

// ---------------------------------------------------------------------------
// One-shot split of all inputs to chunk-tiled hi/lo bf16 planes in ws.
__global__ __launch_bounds__(256, 2)
void split_kernel(const float* __restrict__ imq, const float* __restrict__ imv,
                  const float* __restrict__ txk, const float* __restrict__ txv,
                  const int* __restrict__ tlen, const float* __restrict__ wsf,
                  short* __restrict__ wss) {
    const int ten = blockIdx.y;
    const int jid = blockIdx.x * 256 + threadIdx.x;
    const float* src; float sc; size_t dst; int psz;
    if (ten < 2) {
        int slab = jid >> 13, r = jid & 8191;
        int kc = r >> 8, row = (r >> 2) & 63, ks = r & 3;
        const float* base = (ten == 0) ? txk : txv;
        src = base + (size_t)slab * 65536 + row * 1024 + kc * 32 + ks * 8;
        int nw = tlen[slab];
        if (ten == 0) sc = (row < nw) ? wsf[WS_INVK + slab * 64 + row] : 0.f;
        else          sc = (row < nw) ? 1.f : 0.f;
        dst = (size_t)(ten == 0 ? SP_TK : SP_TV) + (size_t)slab * 131072
            + kc * 2048 + row * 32 + ks * 8;
        psz = 65536;
    } else {
        if (jid >= 786432) return;
        int slab = jid / 6144, r = jid - slab * 6144;
        int kc = r / 192; int rr = r - kc * 192;
        int row = rr >> 2, ks = rr & 3;
        const float* base = (ten == 2) ? imq : imv;
        src = base + (size_t)slab * 49152 + row * 1024 + kc * 32 + ks * 8;
        sc = (ten == 2) ? wsf[WS_INVQ + slab * 48 + row] : 1.f;
        dst = (size_t)(ten == 2 ? SP_Q : SP_V) + (size_t)slab * 98304
            + kc * 1536 + row * 32 + ks * 8;
        psz = 49152;
    }
    float4 x0 = *(const float4*)src;
    float4 x1 = *(const float4*)(src + 4);
    float v[8] = {x0.x, x0.y, x0.z, x0.w, x1.x, x1.y, x1.z, x1.w};
    short8 hv, lv;
#pragma unroll
    for (int i = 0; i < 8; ++i) {
        float a = v[i] * sc;
        u32 h = f2bf(a);
        hv[i] = (short)h;
        lv[i] = (short)f2bf(a - bf2f(h));
    }
    *(short8*)(wss + dst) = hv;
    *(short8*)(wss + dst + psz) = lv;
}

// ---------------------------------------------------------------------------
// Gram matrices: H[t] = tv tv^T (masked), Vg[n] = v v^T.
template <int TS>
__device__ __forceinline__ void gram_body(const float* __restrict__ src,
                                          float* __restrict__ dstf,
                                          u32* __restrict__ dstu,
                                          int mode, int nw, float* sT){
    const int NR = TS * 16;
    int ar = threadIdx.x >> 4, ac = threadIdx.x & 15;
    float acc[TS][TS];
#pragma unroll
    for (int i = 0; i < TS; ++i)
#pragma unroll
        for (int j = 0; j < TS; ++j) acc[i][j] = 0.f;
    for (int kc = 0; kc < 8; ++kc) {
        int k0 = kc * 128;
        for (int jid = threadIdx.x; jid < NR * 32; jid += 256) {
            int row = jid >> 5, c4 = jid & 31;
            float4 x = *(const float4*)(src + row * 1024 + k0 + c4 * 4);
            float sc = (row < nw) ? 1.f : 0.f;
            x.x *= sc; x.y *= sc; x.z *= sc; x.w *= sc;
            *(float4*)&sT[row * 132 + c4 * 4] = x;
        }
        __syncthreads();
#pragma unroll 4
        for (int k4 = 0; k4 < 32; ++k4) {
            float4 av[TS], bv[TS];
#pragma unroll
            for (int i = 0; i < TS; ++i) av[i] = *(const float4*)&sT[(TS*ar + i) * 132 + k4 * 4];
#pragma unroll
            for (int j = 0; j < TS; ++j) bv[j] = *(const float4*)&sT[(TS*ac + j) * 132 + k4 * 4];
#pragma unroll
            for (int i = 0; i < TS; ++i)
#pragma unroll
                for (int j = 0; j < TS; ++j)
                    acc[i][j] += av[i].x*bv[j].x + av[i].y*bv[j].y + av[i].z*bv[j].z + av[i].w*bv[j].w;
        }
        __syncthreads();
    }
#pragma unroll
    for (int i = 0; i < TS; ++i)
#pragma unroll
        for (int j = 0; j < TS; ++j) {
            int idx = (TS*ar + i) * NR + TS*ac + j;
            if (mode) dstu[idx] = packsplit(acc[i][j]);
            else      dstf[idx] = acc[i][j];
        }
}

__global__ __launch_bounds__(256, 2)
void gram_kernel(const float* __restrict__ txv, const float* __restrict__ imv,
                 const int* __restrict__ tlen, float* __restrict__ ws, int mode){
    __shared__ __align__(16) float sT[64 * 132];
    int b = blockIdx.x;
    u32* wsu = (u32*)ws;
    if (b < 128) {
        gram_body<4>(txv + (size_t)b * 65536, ws + WS_H + (size_t)b * 4096,
                     wsu + WS_HU + (size_t)b * 4096, mode, tlen[b], sT);
    } else {
        int n = b - 128;
        gram_body<3>(imv + (size_t)n * 49152, ws + WS_VG + (size_t)n * 2304,
                     wsu + WS_VGU + (size_t)n * 2304, mode, 48, sT);
    }
}

// ---------------------------------------------------------------------------
// Round-3 main kernel: split planes precomputed; A-frags global-direct,
// B staged in LDS with conflict-free b128 writes.
struct AFr { short8 kh[2], kl[2], th[2], tl[2]; };

__device__ __forceinline__ void load_af(AFr& A, const short* tkh, const short* tkl,
                                        const short* tvh, const short* tvl,
                                        int off, int r0, int r1){
    A.kh[0] = *(const short8*)(tkh + off + r0);
    A.kh[1] = *(const short8*)(tkh + off + r1);
    A.kl[0] = *(const short8*)(tkl + off + r0);
    A.kl[1] = *(const short8*)(tkl + off + r1);
    A.th[0] = *(const short8*)(tvh + off + r0);
    A.th[1] = *(const short8*)(tvh + off + r1);
    A.tl[0] = *(const short8*)(tvl + off + r0);
    A.tl[1] = *(const short8*)(tvl + off + r1);
}

__device__ __forceinline__ void mfma_step(const AFr& A, const short* stg,
                                          int nl, int m16, int quad,
                                          f32x4 (&accS)[2][3], f32x4 (&accG)[2][3]){
#pragma unroll
    for (int j = 0; j < 3; ++j) {
        int o = (nl * 48 + 16 * j + m16) * 40 + quad * 8;
        short8 bqh = *(const short8*)(stg + o);
        short8 bql = *(const short8*)(stg + 3840 + o);
        short8 bvh = *(const short8*)(stg + 7680 + o);
        short8 bvl = *(const short8*)(stg + 11520 + o);
#pragma unroll
        for (int i = 0; i < 2; ++i) {
            accS[i][j] = MFMA(A.kh[i], bqh, accS[i][j]);
            accS[i][j] = MFMA(A.kh[i], bql, accS[i][j]);
            accS[i][j] = MFMA(A.kl[i], bqh, accS[i][j]);
            accG[i][j] = MFMA(A.th[i], bvh, accG[i][j]);
            accG[i][j] = MFMA(A.th[i], bvl, accG[i][j]);
            accG[i][j] = MFMA(A.tl[i], bvh, accG[i][j]);
        }
    }
}

__global__ __launch_bounds__(256, 2)
void loss_mfma2(const int* __restrict__ tlen, const float* __restrict__ ws,
                float* __restrict__ out) {
    const int npair = blockIdx.x;
    const int t     = blockIdx.y;
    const int n0    = npair * 2;
    const int tid   = threadIdx.x;
    const int lane  = tid & 63;
    const int w     = tid >> 6;
    const int nl    = w >> 1;
    const int hh    = w & 1;
    const int quad  = lane >> 4;
    const int m16   = lane & 15;

    __shared__ __align__(16) float Sm[19776];
    short* stg   = (short*)Sm;                  // B staging: qh/ql/vh/vl [96][40]
    u32*   A1w   = (u32*)Sm;                    // [2][48][68] (after K-loop)
    u32*   A2w   = ((u32*)Sm) + 6528;           // [2][64][48]
    float* P     = Sm + 12672;                  // [2][64][49]
    u32*   HVw   = (u32*)(Sm + 12672);          // H [64][68] then Vg [2][48][52]
    float* sNl   = Sm + 19104;
    float* sNr   = Sm + 19232;
    float* sD1   = Sm + 19328;
    float* sS1   = Sm + 19424;
    float* sD2   = Sm + 19520;
    float* sS2   = Sm + 19648;

    const int nw = tlen[t];
    const float nwf = (float)nw;
    const short* wss = (const short*)ws;
    const u32*   wsu = (const u32*)ws;

    // B staging descriptors: 6 x 16B jobs/thread (qh,ql,vh,vl planes)
    const short* bsrc[6]; int bdst[6];
#pragma unroll
    for (int it = 0; it < 6; ++it) {
        int jid = tid + 256 * it;
        int p = jid / 384; int rr = jid - p * 384;
        int row = rr >> 2, ks = rr & 3;
        int img = row >= 48; int grow = row - 48 * img;
        bsrc[it] = wss + (p < 2 ? SP_Q : SP_V) + (size_t)(n0 + img) * 98304
                 + (size_t)(p & 1) * 49152 + grow * 32 + ks * 8;
        bdst[it] = p * 3840 + row * 40 + ks * 8;
    }

    // A-frag global bases (chunk-tiled planes)
    const short* tkh = wss + SP_TK + (size_t)t * 131072;
    const short* tkl = tkh + 65536;
    const short* tvh = wss + SP_TV + (size_t)t * 131072;
    const short* tvl = tvh + 65536;
    const int ar0 = (32 * hh + m16) * 32 + quad * 8;
    const int ar1 = ar0 + 512;

    f32x4 accS[2][3], accG[2][3];
    f32x4 zf = {0.f, 0.f, 0.f, 0.f};
#pragma unroll
    for (int i = 0; i < 2; ++i)
#pragma unroll
        for (int j = 0; j < 3; ++j) { accS[i][j] = zf; accG[i][j] = zf; }

    short8 bj[6];
#pragma unroll
    for (int it = 0; it < 6; ++it) bj[it] = *(const short8*)(bsrc[it]);
    AFr Ae, Ao;
    load_af(Ae, tkh, tkl, tvh, tvl, 0, ar0, ar1);

    for (int kc2 = 0; kc2 < 16; ++kc2) {
        const int kc = kc2 * 2;
        // even sub-iter: consume Ae, prefetch Ao/bj for kc+1
        {
#pragma unroll
            for (int it = 0; it < 6; ++it) *(short8*)(stg + bdst[it]) = bj[it];
            __syncthreads();
            int bo = (kc + 1) * 1536;
#pragma unroll
            for (int it = 0; it < 6; ++it) bj[it] = *(const short8*)(bsrc[it] + bo);
            load_af(Ao, tkh, tkl, tvh, tvl, (kc + 1) * 2048, ar0, ar1);
            mfma_step(Ae, stg, nl, m16, quad, accS, accG);
            __syncthreads();
        }
        // odd sub-iter: consume Ao, prefetch Ae/bj for kc+2
        {
#pragma unroll
            for (int it = 0; it < 6; ++it) *(short8*)(stg + bdst[it]) = bj[it];
            __syncthreads();
            if (kc2 < 15) {
                int bo = (kc + 2) * 1536;
#pragma unroll
                for (int it = 0; it < 6; ++it) bj[it] = *(const short8*)(bsrc[it] + bo);
                load_af(Ae, tkh, tkl, tvh, tvl, (kc + 2) * 2048, ar0, ar1);
            }
            mfma_step(Ao, stg, nl, m16, quad, accS, accG);
            __syncthreads();
        }
    }

    // ---- P = leaky_relu(S) ----
#pragma unroll
    for (int i = 0; i < 2; ++i)
#pragma unroll
        for (int j = 0; j < 3; ++j)
#pragma unroll
            for (int v = 0; v < 4; ++v) {
                int l = 32 * hh + 16 * i + quad * 4 + v;
                int r = 16 * j + m16;
                float x = accS[i][j][v];
                P[nl * 3136 + l * 49 + r] = (x > 0.f) ? x : 0.1f * x;
            }
    __syncthreads();

    // ---- norms + zero accumulators ----
    if (tid < 128) {
        int n = tid >> 6, l = tid & 63;
        float s = 0.f;
#pragma unroll 4
        for (int r = 0; r < 48; ++r) { float x = P[n*3136 + l*49 + r]; s += x * x; }
        sNl[n * 64 + l] = sqrtf(s) + FEPS;
    } else if (tid < 224) {
        int i = tid - 128; int n = i >= 48; int r = i - 48 * n;
        float s = 0.f;
#pragma unroll 4
        for (int l = 0; l < 64; ++l) { float x = P[n*3136 + l*49 + r]; s += x * x; }
        sNr[n * 48 + r] = sqrtf(s) + FEPS;
    } else {
        for (int k = tid - 224; k < 448; k += 32) sD1[k] = 0.f;
    }
    __syncthreads();

    // ---- softmax + focal ----
    if (tid < 128) {
        int n = tid >> 6, l = tid & 63;
        u32* row = A2w + n * 3072 + l * 48;
        if (l < nw) {
            float a[48]; float mx = -1e30f;
            const float* Pr = P + n * 3136 + l * 49;
#pragma unroll
            for (int r = 0; r < 48; ++r) {
                float x = LAMB * Pr[r] / sNr[n * 48 + r];
                a[r] = x; mx = fmaxf(mx, x);
            }
            float se = 0.f;
#pragma unroll
            for (int r = 0; r < 48; ++r) { float e = __expf(a[r] - mx); a[r] = e; se += e; }
            float suma = 0.f;
#pragma unroll
            for (int r = 0; r < 48; ++r) { float x = a[r] / se; a[r] = x; suma += x; }
            float s2 = 0.f;
#pragma unroll
            for (int r = 0; r < 48; ++r) if (a[r] * 48.f - suma > 0.f) s2 += a[r];
            float ri = (s2 > 0.f) ? 1.f / s2 : 1.f;
#pragma unroll
            for (int r = 0; r < 48; ++r) {
                float x = (a[r] * 48.f - suma > 0.f) ? a[r] * ri : 0.f;
                row[r] = packsplit(x);
            }
        } else {
#pragma unroll
            for (int r = 0; r < 48; ++r) row[r] = 0u;
        }
    } else if (tid < 224) {
        int i = tid - 128; int n = i >= 48; int r = i - 48 * n;
        float a[64]; float mx = -1e30f;
#pragma unroll
        for (int l = 0; l < 64; ++l) {
            float x = (l < nw) ? (LAMB * P[n*3136 + l*49 + r] / sNl[n * 64 + l]) : -1e30f;
            a[l] = x; mx = fmaxf(mx, x);
        }
        float se = 0.f;
#pragma unroll
        for (int l = 0; l < 64; ++l) { float e = __expf(a[l] - mx); a[l] = e; se += e; }
        float suma = 0.f;
#pragma unroll
        for (int l = 0; l < 64; ++l) { float x = a[l] / se; a[l] = x; suma += x; }
        float s2 = 0.f;
#pragma unroll
        for (int l = 0; l < 64; ++l) if (a[l] * nwf - suma > 0.f) s2 += a[l];
        float ri = (s2 > 0.f) ? 1.f / s2 : 1.f;
        u32* row = A1w + n * 3264 + r * 68;
#pragma unroll
        for (int l = 0; l < 64; ++l) {
            float x = (a[l] * nwf - suma > 0.f) ? a[l] * ri : 0.f;
            row[l] = packsplit(x);
        }
    }
    __syncthreads();

    // ---- stage H (precomputed packed split, plain copy) ----
    {
        const u32* Hg = wsu + WS_HU + (size_t)t * 4096;
        for (int jid = tid; jid < 1024; jid += 256) {
            int row = jid >> 4, c = jid & 15;
            *(uintx4*)&HVw[row * 68 + c * 4] = *(const uintx4*)&Hg[row * 64 + c * 4];
        }
    }
    __syncthreads();

    // ---- Y = H @ A1^T; s1/d1 reduction ----
    f32x4 accY[2][3];
    f32x4 zf2 = {0.f, 0.f, 0.f, 0.f};
#pragma unroll
    for (int i = 0; i < 2; ++i)
#pragma unroll
        for (int j = 0; j < 3; ++j) accY[i][j] = zf2;
#pragma unroll
    for (int ks = 0; ks < 2; ++ks) {
        int kb = ks * 32 + quad * 8;
        short8 Ah[2], Al[2];
#pragma unroll
        for (int i = 0; i < 2; ++i) {
            int row = 32 * hh + 16 * i + m16;
            uintx4 wa = *(const uintx4*)&HVw[row * 68 + kb];
            uintx4 wb = *(const uintx4*)&HVw[row * 68 + kb + 4];
            unpk(wa, wb, Ah[i], Al[i]);
        }
        short8 Bh[3], Bl[3];
#pragma unroll
        for (int j = 0; j < 3; ++j) {
            int base = nl * 3264 + (16 * j + m16) * 68 + kb;
            uintx4 wa = *(const uintx4*)&A1w[base];
            uintx4 wb = *(const uintx4*)&A1w[base + 4];
            unpk(wa, wb, Bh[j], Bl[j]);
        }
#pragma unroll
        for (int i = 0; i < 2; ++i)
#pragma unroll
            for (int j = 0; j < 3; ++j) {
                accY[i][j] = MFMA(Ah[i], Bh[j], accY[i][j]);
                accY[i][j] = MFMA(Ah[i], Bl[j], accY[i][j]);
                accY[i][j] = MFMA(Al[i], Bh[j], accY[i][j]);
            }
    }
    {
        float td[3] = {0.f, 0.f, 0.f}, ts[3] = {0.f, 0.f, 0.f};
#pragma unroll
        for (int i = 0; i < 2; ++i)
#pragma unroll
            for (int v = 0; v < 4; ++v) {
                int l = 32 * hh + 16 * i + quad * 4 + v;
#pragma unroll
                for (int j = 0; j < 3; ++j) {
                    u32 wv = A1w[nl * 3264 + (16 * j + m16) * 68 + l];
                    float av = bf2f(wv & 0xffffu) + bf2f(wv >> 16);
                    td[j] += av * accG[i][j][v];
                    ts[j] += av * accY[i][j][v];
                }
            }
#pragma unroll
        for (int j = 0; j < 3; ++j) {
            float d = td[j]; d += __shfl_xor(d, 16, 64); d += __shfl_xor(d, 32, 64);
            float s = ts[j]; s += __shfl_xor(s, 16, 64); s += __shfl_xor(s, 32, 64);
            if (quad == 0) {
                atomicAdd(&sD1[nl * 48 + 16 * j + m16], d);
                atomicAdd(&sS1[nl * 48 + 16 * j + m16], s);
            }
        }
    }
    __syncthreads();

    // ---- stage Vg (precomputed packed split, plain copy) ----
    {
        const u32* Vgg = wsu + WS_VGU + (size_t)n0 * 2304;
        for (int jid = tid; jid < 1152; jid += 256) {
            int img = jid >= 576; int j2 = jid - 576 * img;
            int row = j2 / 12, c = j2 - row * 12;
            *(uintx4*)&HVw[img * 2496 + row * 52 + c * 4] =
                *(const uintx4*)&Vgg[(size_t)img * 2304 + row * 48 + c * 4];
        }
    }
    __syncthreads();

    // ---- Y2 = Vg @ A2^T; s2/d2 ----
    f32x4 accY2[3][2];
#pragma unroll
    for (int i = 0; i < 3; ++i)
#pragma unroll
        for (int j = 0; j < 2; ++j) accY2[i][j] = zf2;
    const u32* VgW = HVw + nl * 2496;
#pragma unroll
    for (int ks = 0; ks < 2; ++ks) {
        const bool dead = (ks == 1) && (quad >= 2);
        const int kb = (ks == 0) ? quad * 8 : 32 + (quad & 1) * 8;
        short8 Ah2[3], Al2[3];
#pragma unroll
        for (int i = 0; i < 3; ++i) {
            uintx4 wa = {0,0,0,0}, wb = {0,0,0,0};
            if (!dead) {
                int row = 16 * i + m16;
                wa = *(const uintx4*)&VgW[row * 52 + kb];
                wb = *(const uintx4*)&VgW[row * 52 + kb + 4];
            }
            unpk(wa, wb, Ah2[i], Al2[i]);
        }
        short8 Bh2[2], Bl2[2];
#pragma unroll
        for (int j = 0; j < 2; ++j) {
            uintx4 wa = {0,0,0,0}, wb = {0,0,0,0};
            if (!dead) {
                int l = 32 * hh + 16 * j + m16;
                wa = *(const uintx4*)&A2w[nl * 3072 + l * 48 + kb];
                wb = *(const uintx4*)&A2w[nl * 3072 + l * 48 + kb + 4];
            }
            unpk(wa, wb, Bh2[j], Bl2[j]);
        }
#pragma unroll
        for (int i = 0; i < 3; ++i)
#pragma unroll
            for (int j = 0; j < 2; ++j) {
                accY2[i][j] = MFMA(Ah2[i], Bh2[j], accY2[i][j]);
                accY2[i][j] = MFMA(Ah2[i], Bl2[j], accY2[i][j]);
                accY2[i][j] = MFMA(Al2[i], Bh2[j], accY2[i][j]);
            }
    }
    {
        float u[2] = {0.f, 0.f};
#pragma unroll
        for (int i = 0; i < 3; ++i)
#pragma unroll
            for (int v = 0; v < 4; ++v) {
                int r = 16 * i + quad * 4 + v;
#pragma unroll
                for (int j = 0; j < 2; ++j) {
                    int l = 32 * hh + 16 * j + m16;
                    u32 wv = A2w[nl * 3072 + l * 48 + r];
                    float av = bf2f(wv & 0xffffu) + bf2f(wv >> 16);
                    u[j] += av * accY2[i][j][v];
                }
            }
#pragma unroll
        for (int j = 0; j < 2; ++j) {
            float s = u[j]; s += __shfl_xor(s, 16, 64); s += __shfl_xor(s, 32, 64);
            if (quad == 0) sS2[nl * 64 + 32 * hh + 16 * j + m16] = s;
        }
        float ud[2][4];
#pragma unroll
        for (int i = 0; i < 2; ++i)
#pragma unroll
            for (int v = 0; v < 4; ++v) ud[i][v] = 0.f;
#pragma unroll
        for (int i = 0; i < 2; ++i)
#pragma unroll
            for (int v = 0; v < 4; ++v) {
                int l = 32 * hh + 16 * i + quad * 4 + v;
#pragma unroll
                for (int j = 0; j < 3; ++j) {
                    u32 wv = A2w[nl * 3072 + l * 48 + (16 * j + m16)];
                    float av = bf2f(wv & 0xffffu) + bf2f(wv >> 16);
                    ud[i][v] += av * accG[i][j][v];
                }
            }
#pragma unroll
        for (int i = 0; i < 2; ++i)
#pragma unroll
            for (int v = 0; v < 4; ++v) {
                float d = ud[i][v];
                d += __shfl_xor(d, 1, 64); d += __shfl_xor(d, 2, 64);
                d += __shfl_xor(d, 4, 64); d += __shfl_xor(d, 8, 64);
                if (m16 == 0) sD2[nl * 64 + 32 * hh + 16 * i + quad * 4 + v] = d;
            }
    }
    __syncthreads();

    // ---- cosine epilogue ----
    if (tid < 96) {
        int n = tid >= 48; int r = tid - 48 * n;
        float wn = sqrtf(sS1[n * 48 + r]);
        float dh = sD1[n * 48 + r] / (wn + FEPS);
        float nh = wn / (wn + FEPS);
        float vn = ws[WS_VN + (n0 + n) * 48 + r];
        sD1[n * 48 + r] = dh / fmaxf(vn * nh, FEPS);
    } else if (tid >= 128) {
        int i = tid - 128; int n = i >> 6, l = i & 63;
        if (l < nw) {
            float wn = sqrtf(sS2[n * 64 + l]);
            float dh = sD2[n * 64 + l] / (wn + FEPS);
            float nh = wn / (wn + FEPS);
            float tn = ws[WS_TVN + t * 64 + l];
            sD2[n * 64 + l] = dh / fmaxf(tn * nh, FEPS);
        }
    }
    __syncthreads();
    if (tid < 2) {
        float s = 0.f;
        for (int r = 0; r < 48; ++r) s += sD1[tid * 48 + r];
        out[(size_t)(n0 + tid) * NTXT + t] = s / 48.f;
    } else if (tid == 64 || tid == 65) {
        int n = tid - 64;
        float s = 0.f;
        for (int l = 0; l < nw; ++l) s += sD2[n * 64 + l];
        out[(size_t)(NIMG * NTXT) + (size_t)(n0 + n) * NTXT + t] = s / nwf;
    }
}

// ---------------------------------------------------------------------------
// Round-2 verified fallback (used only if ws too small for split planes).
__global__ __launch_bounds__(256, 2)
void loss_mfma(const float* __restrict__ imq, const float* __restrict__ imv,
               const float* __restrict__ txk, const float* __restrict__ txv,
               const int* __restrict__ tlen, const float* __restrict__ ws,
               float* __restrict__ out) {
    const int npair = blockIdx.x;
    const int t     = blockIdx.y;
    const int n0    = npair * 2;
    const int tid   = threadIdx.x;
    const int lane  = tid & 63;
    const int w     = tid >> 6;
    const int nl    = w >> 1;
    const int hh    = w & 1;
    const int quad  = lane >> 4;
    const int m16   = lane & 15;

    __shared__ __align__(16) float Sm[19904];
    short* stage = (short*)Sm;
    u32*   A1w   = (u32*)Sm;
    u32*   A2w   = ((u32*)Sm) + 6528;
    float* P     = Sm + 12800;
    u32*   HVw   = (u32*)(Sm + 12800);
    float* sInvK = Sm + 19072;
    float* sInvQ = sInvK + 64;
    float* sNl   = sInvQ + 96;
    float* sNr   = sNl + 128;
    float* sD1   = sNr + 96;
    float* sS1   = sD1 + 96;
    float* sD2   = sS1 + 96;
    float* sS2   = sD2 + 128;

    const int nw = tlen[t];
    const float nwf = (float)nw;
    if (tid < 64) sInvK[tid] = ws[WS_INVK + t * 64 + tid];
    else if (tid < 160) {
        int i = tid - 64; int nn = i >= 48; int r = i - 48 * nn;
        sInvQ[i] = ws[WS_INVQ + (n0 + nn) * 48 + r];
    }
    __syncthreads();

    const float* tkb = txk + (size_t)t * 65536;
    const float* tvb = txv + (size_t)t * 65536;
    const float* qb0 = imq + (size_t)n0 * 49152;
    const float* vb0 = imv + (size_t)n0 * 49152;

    const float* sp[10]; int di[10]; float scl[10];
#pragma unroll
    for (int it = 0; it < 10; ++it) {
        int jid = tid + 256 * it;
        const float* s; int plane; int row, c4; float sc;
        if (it < 2) {
            row = jid >> 3; c4 = jid & 7;
            s = tkb + row * 1024 + c4 * 4;
            sc = (row < nw) ? sInvK[row] : 0.f;
            plane = PTKH;
        } else if (it < 4) {
            int j2 = jid - 512; row = j2 >> 3; c4 = j2 & 7;
            s = tvb + row * 1024 + c4 * 4;
            sc = (row < nw) ? 1.f : 0.f;
            plane = PTVH;
        } else if (it < 7) {
            int j2 = jid - 1024; row = j2 >> 3; c4 = j2 & 7;
            s = qb0 + row * 1024 + c4 * 4;
            sc = sInvQ[row];
            plane = PQH;
        } else {
            int j2 = jid - 1792; row = j2 >> 3; c4 = j2 & 7;
            s = vb0 + row * 1024 + c4 * 4;
            sc = 1.f;
            plane = PVH;
        }
        sp[it] = s; di[it] = plane + row * PSTR + c4 * 4; scl[it] = sc;
    }

    f32x4 accS[2][3], accG[2][3];
    f32x4 zf = {0.f, 0.f, 0.f, 0.f};
#pragma unroll
    for (int i = 0; i < 2; ++i)
#pragma unroll
        for (int j = 0; j < 3; ++j) { accS[i][j] = zf; accG[i][j] = zf; }

    float4 pf[10];
#pragma unroll
    for (int it = 0; it < 10; ++it) pf[it] = *(const float4*)(sp[it]);

    for (int kc = 0; kc < 32; ++kc) {
#pragma unroll
        for (int it = 0; it < 10; ++it) split_store(stage, di[it], pf[it], scl[it]);
        __syncthreads();
        if (kc < 31) {
            const int ko = (kc + 1) * 32;
#pragma unroll
            for (int it = 0; it < 10; ++it) pf[it] = *(const float4*)(sp[it] + ko);
        }
        short8 akh[2], akl[2], ath[2], atl[2];
#pragma unroll
        for (int i = 0; i < 2; ++i) {
            int rb = 32 * hh + 16 * i;
            akh[i] = frag_ld(stage, PTKH,         rb, m16, quad);
            akl[i] = frag_ld(stage, PTKH + LOGAP, rb, m16, quad);
            ath[i] = frag_ld(stage, PTVH,         rb, m16, quad);
            atl[i] = frag_ld(stage, PTVH + LOGAP, rb, m16, quad);
        }
        short8 bqh[3], bql[3], bvh[3], bvl[3];
#pragma unroll
        for (int j = 0; j < 3; ++j) {
            int rb = nl * 48 + 16 * j;
            bqh[j] = frag_ld(stage, PQH,         rb, m16, quad);
            bql[j] = frag_ld(stage, PQH + LOGAP, rb, m16, quad);
            bvh[j] = frag_ld(stage, PVH,         rb, m16, quad);
            bvl[j] = frag_ld(stage, PVH + LOGAP, rb, m16, quad);
        }
#pragma unroll
        for (int i = 0; i < 2; ++i)
#pragma unroll
            for (int j = 0; j < 3; ++j) {
                accS[i][j] = MFMA(akh[i], bqh[j], accS[i][j]);
                accS[i][j] = MFMA(akh[i], bql[j], accS[i][j]);
                accS[i][j] = MFMA(akl[i], bqh[j], accS[i][j]);
                accG[i][j] = MFMA(ath[i], bvh[j], accG[i][j]);
                accG[i][j] = MFMA(ath[i], bvl[j], accG[i][j]);
                accG[i][j] = MFMA(atl[i], bvh[j], accG[i][j]);
            }
        __syncthreads();
    }

#pragma unroll
    for (int i = 0; i < 2; ++i)
#pragma unroll
        for (int j = 0; j < 3; ++j)
#pragma unroll
            for (int v = 0; v < 4; ++v) {
                int l = 32 * hh + 16 * i + quad * 4 + v;
                int r = 16 * j + m16;
                float x = accS[i][j][v];
                P[nl * 3136 + l * 49 + r] = (x > 0.f) ? x : 0.1f * x;
            }
    __syncthreads();

    if (tid < 128) {
        int n = tid >> 6, l = tid & 63;
        float s = 0.f;
#pragma unroll 4
        for (int r = 0; r < 48; ++r) { float x = P[n*3136 + l*49 + r]; s += x * x; }
        sNl[n * 64 + l] = sqrtf(s) + FEPS;
    } else if (tid < 224) {
        int i = tid - 128; int n = i >= 48; int r = i - 48 * n;
        float s = 0.f;
#pragma unroll 4
        for (int l = 0; l < 64; ++l) { float x = P[n*3136 + l*49 + r]; s += x * x; }
        sNr[n * 48 + r] = sqrtf(s) + FEPS;
    } else {
        for (int k = tid - 224; k < 448; k += 32) sD1[k] = 0.f;
    }
    __syncthreads();

    if (tid < 128) {
        int n = tid >> 6, l = tid & 63;
        u32* row = A2w + n * 3072 + l * 48;
        if (l < nw) {
            float a[48]; float mx = -1e30f;
            const float* Pr = P + n * 3136 + l * 49;
#pragma unroll
            for (int r = 0; r < 48; ++r) {
                float x = LAMB * Pr[r] / sNr[n * 48 + r];
                a[r] = x; mx = fmaxf(mx, x);
            }
            float se = 0.f;
#pragma unroll
            for (int r = 0; r < 48; ++r) { float e = __expf(a[r] - mx); a[r] = e; se += e; }
            float suma = 0.f;
#pragma unroll
            for (int r = 0; r < 48; ++r) { float x = a[r] / se; a[r] = x; suma += x; }
            float s2 = 0.f;
#pragma unroll
            for (int r = 0; r < 48; ++r) if (a[r] * 48.f - suma > 0.f) s2 += a[r];
            float ri = (s2 > 0.f) ? 1.f / s2 : 1.f;
#pragma unroll
            for (int r = 0; r < 48; ++r) {
                float x = (a[r] * 48.f - suma > 0.f) ? a[r] * ri : 0.f;
                row[r] = packsplit(x);
            }
        } else {
#pragma unroll
            for (int r = 0; r < 48; ++r) row[r] = 0u;
        }
    } else if (tid < 224) {
        int i = tid - 128; int n = i >= 48; int r = i - 48 * n;
        float a[64]; float mx = -1e30f;
#pragma unroll
        for (int l = 0; l < 64; ++l) {
            float x = (l < nw) ? (LAMB * P[n*3136 + l*49 + r] / sNl[n * 64 + l]) : -1e30f;
            a[l] = x; mx = fmaxf(mx, x);
        }
        float se = 0.f;
#pragma unroll
        for (int l = 0; l < 64; ++l) { float e = __expf(a[l] - mx); a[l] = e; se += e; }
        float suma = 0.f;
#pragma unroll
        for (int l = 0; l < 64; ++l) { float x = a[l] / se; a[l] = x; suma += x; }
        float s2 = 0.f;
#pragma unroll
        for (int l = 0; l < 64; ++l) if (a[l] * nwf - suma > 0.f) s2 += a[l];
        float ri = (s2 > 0.f) ? 1.f / s2 : 1.f;
        u32* row = A1w + n * 3264 + r * 68;
#pragma unroll
        for (int l = 0; l < 64; ++l) {
            float x = (a[l] * nwf - suma > 0.f) ? a[l] * ri : 0.f;
            row[l] = packsplit(x);
        }
    }
    __syncthreads();

    {
        const float* Hg = ws + WS_H + (size_t)t * 4096;
        for (int jid = tid; jid < 1024; jid += 256) {
            int row = jid >> 4, c4 = jid & 15;
            float4 x = *(const float4*)(Hg + row * 64 + c4 * 4);
            uintx4 p; p.x = packsplit(x.x); p.y = packsplit(x.y);
            p.z = packsplit(x.z); p.w = packsplit(x.w);
            *(uintx4*)&HVw[row * 68 + c4 * 4] = p;
        }
    }
    __syncthreads();

    f32x4 accY[2][3];
#pragma unroll
    for (int i = 0; i < 2; ++i)
#pragma unroll
        for (int j = 0; j < 3; ++j) accY[i][j] = zf;
#pragma unroll
    for (int ks = 0; ks < 2; ++ks) {
        int kb = ks * 32 + quad * 8;
        short8 Ah[2], Al[2];
#pragma unroll
        for (int i = 0; i < 2; ++i) {
            int row = 32 * hh + 16 * i + m16;
            uintx4 wa = *(const uintx4*)&HVw[row * 68 + kb];
            uintx4 wb = *(const uintx4*)&HVw[row * 68 + kb + 4];
            unpk(wa, wb, Ah[i], Al[i]);
        }
        short8 Bh[3], Bl[3];
#pragma unroll
        for (int j = 0; j < 3; ++j) {
            int base = nl * 3264 + (16 * j + m16) * 68 + kb;
            uintx4 wa = *(const uintx4*)&A1w[base];
            uintx4 wb = *(const uintx4*)&A1w[base + 4];
            unpk(wa, wb, Bh[j], Bl[j]);
        }
#pragma unroll
        for (int i = 0; i < 2; ++i)
#pragma unroll
            for (int j = 0; j < 3; ++j) {
                accY[i][j] = MFMA(Ah[i], Bh[j], accY[i][j]);
                accY[i][j] = MFMA(Ah[i], Bl[j], accY[i][j]);
                accY[i][j] = MFMA(Al[i], Bh[j], accY[i][j]);
            }
    }
    {
        float td[3] = {0.f, 0.f, 0.f}, ts[3] = {0.f, 0.f, 0.f};
#pragma unroll
        for (int i = 0; i < 2; ++i)
#pragma unroll
            for (int v = 0; v < 4; ++v) {
                int l = 32 * hh + 16 * i + quad * 4 + v;
#pragma unroll
                for (int j = 0; j < 3; ++j) {
                    u32 wv = A1w[nl * 3264 + (16 * j + m16) * 68 + l];
                    float av = bf2f(wv & 0xffffu) + bf2f(wv >> 16);
                    td[j] += av * accG[i][j][v];
                    ts[j] += av * accY[i][j][v];
                }
            }
#pragma unroll
        for (int j = 0; j < 3; ++j) {
            float d = td[j]; d += __shfl_xor(d, 16, 64); d += __shfl_xor(d, 32, 64);
            float s = ts[j]; s += __shfl_xor(s, 16, 64); s += __shfl_xor(s, 32, 64);
            if (quad == 0) {
                atomicAdd(&sD1[nl * 48 + 16 * j + m16], d);
                atomicAdd(&sS1[nl * 48 + 16 * j + m16], s);
            }
        }
    }
    __syncthreads();

    {
        const float* Vgg = ws + WS_VG + (size_t)n0 * 2304;
        for (int jid = tid; jid < 1152; jid += 256) {
            int nn = jid >= 576; int j2 = jid - 576 * nn;
            int row = j2 / 12, c4 = j2 % 12;
            float4 x = *(const float4*)(Vgg + nn * 2304 + row * 48 + c4 * 4);
            uintx4 p; p.x = packsplit(x.x); p.y = packsplit(x.y);
            p.z = packsplit(x.z); p.w = packsplit(x.w);
            *(uintx4*)&HVw[nn * 2496 + row * 52 + c4 * 4] = p;
        }
    }
    __syncthreads();

    f32x4 accY2[3][2];
#pragma unroll
    for (int i = 0; i < 3; ++i)
#pragma unroll
        for (int j = 0; j < 2; ++j) accY2[i][j] = zf;
    const u32* VgW = HVw + nl * 2496;
#pragma unroll
    for (int ks = 0; ks < 2; ++ks) {
        const bool dead = (ks == 1) && (quad >= 2);
        const int kb = (ks == 0) ? quad * 8 : 32 + (quad & 1) * 8;
        short8 Ah2[3], Al2[3];
#pragma unroll
        for (int i = 0; i < 3; ++i) {
            uintx4 wa = {0,0,0,0}, wb = {0,0,0,0};
            if (!dead) {
                int row = 16 * i + m16;
                wa = *(const uintx4*)&VgW[row * 52 + kb];
                wb = *(const uintx4*)&VgW[row * 52 + kb + 4];
            }
            unpk(wa, wb, Ah2[i], Al2[i]);
        }
        short8 Bh2[2], Bl2[2];
#pragma unroll
        for (int j = 0; j < 2; ++j) {
            uintx4 wa = {0,0,0,0}, wb = {0,0,0,0};
            if (!dead) {
                int l = 32 * hh + 16 * j + m16;
                wa = *(const uintx4*)&A2w[nl * 3072 + l * 48 + kb];
                wb = *(const uintx4*)&A2w[nl * 3072 + l * 48 + kb + 4];
            }
            unpk(wa, wb, Bh2[j], Bl2[j]);
        }
#pragma unroll
        for (int i = 0; i < 3; ++i)
#pragma unroll
            for (int j = 0; j < 2; ++j) {
                accY2[i][j] = MFMA(Ah2[i], Bh2[j], accY2[i][j]);
                accY2[i][j] = MFMA(Ah2[i], Bl2[j], accY2[i][j]);
                accY2[i][j] = MFMA(Al2[i], Bh2[j], accY2[i][j]);
            }
    }
    {
        float u[2] = {0.f, 0.f};
#pragma unroll
        for (int i = 0; i < 3; ++i)
#pragma unroll
            for (int v = 0; v < 4; ++v) {
                int r = 16 * i + quad * 4 + v;
#pragma unroll
                for (int j = 0; j < 2; ++j) {
                    int l = 32 * hh + 16 * j + m16;
                    u32 wv = A2w[nl * 3072 + l * 48 + r];
                    float av = bf2f(wv & 0xffffu) + bf2f(wv >> 16);
                    u[j] += av * accY2[i][j][v];
                }
            }
#pragma unroll
        for (int j = 0; j < 2; ++j) {
            float s = u[j]; s += __shfl_xor(s, 16, 64); s += __shfl_xor(s, 32, 64);
            if (quad == 0) sS2[nl * 64 + 32 * hh + 16 * j + m16] = s;
        }
        float ud[2][4];
#pragma unroll
        for (int i = 0; i < 2; ++i)
#pragma unroll
            for (int v = 0; v < 4; ++v) ud[i][v] = 0.f;
#pragma unroll
        for (int i = 0; i < 2; ++i)
#pragma unroll
            for (int v = 0; v < 4; ++v) {
                int l = 32 * hh + 16 * i + quad * 4 + v;
#pragma unroll
                for (int j = 0; j < 3; ++j) {
                    u32 wv = A2w[nl * 3072 + l * 48 + (16 * j + m16)];
                    float av = bf2f(wv & 0xffffu) + bf2f(wv >> 16);
                    ud[i][v] += av * accG[i][j][v];
                }
            }
#pragma unroll
        for (int i = 0; i < 2; ++i)
#pragma unroll
            for (int v = 0; v < 4; ++v) {
                float d = ud[i][v];
                d += __shfl_xor(d, 1, 64); d += __shfl_xor(d, 2, 64);
                d += __shfl_xor(d, 4, 64); d += __shfl_xor(d, 8, 64);
                if (m16 == 0) sD2[nl * 64 + 32 * hh + 16 * i + quad * 4 + v] = d;
            }
    }
    __syncthreads();

    if (tid < 96) {
        int n = tid >= 48; int r = tid - 48 * n;
        float wn = sqrtf(sS1[n * 48 + r]);
        float dh = sD1[n * 48 + r] / (wn + FEPS);
        float nh = wn / (wn + FEPS);
        float vn = ws[WS_VN + (n0 + n) * 48 + r];
        sD1[n * 48 + r] = dh / fmaxf(vn * nh, FEPS);
    } else if (tid >= 128) {
        int i = tid - 128; int n = i >> 6, l = i & 63;
        if (l < nw) {
            float wn = sqrtf(sS2[n * 64 + l]);
            float dh = sD2[n * 64 + l] / (wn + FEPS);
            float nh = wn / (wn + FEPS);
            float tn = ws[WS_TVN + t * 64 + l];
            sD2[n * 64 + l] = dh / fmaxf(tn * nh, FEPS);
        }
    }
    __syncthreads();
    if (tid < 2) {
        float s = 0.f;
        for (int r = 0; r < 48; ++r) s += sD1[tid * 48 + r];
        out[(size_t)(n0 + tid) * NTXT + t] = s / 48.f;
    } else if (tid == 64 || tid == 65) {
        int n = tid - 64;
        float s = 0.f;
        for (int l = 0; l < nw; ++l) s += sD2[n * 64 + l];
        out[(size_t)(NIMG * NTXT) + (size_t)(n0 + n) * NTXT + t] = s / nwf;
    }
}

extern "C" void kernel_launch(void* const* d_in, const int* in_sizes, int n_in,
                              void* d_out, int out_size, void* d_ws, size_t ws_size,
                              hipStream_t stream) {
    (void)in_sizes; (void)n_in; (void)out_size;
    const float* imq = (const float*)d_in[0];
    const float* imv = (const float*)d_in[1];
    const float* txk = (const float*)d_in[2];
    const float* txv = (const float*)d_in[3];
    const int*   tln = (const int*)d_in[4];
    float* out = (float*)d_out;
    float* ws  = (float*)d_ws;

    prep_norms<<<7168, 256, 0, stream>>>(imq, imv, txk, txv, ws);
    if (ws_size >= WS_BIG_BYTES) {
        split_kernel<<<dim3(4096, 4), 256, 0, stream>>>(imq, imv, txk, txv, tln,
                                                        ws, (short*)d_ws);
        gram_kernel<<<256, 256, 0, stream>>>(txv, imv, tln, ws, 1);
        dim3 grid(64, 128);
        loss_mfma2<<<grid, 256, 0, stream>>>(tln, ws, out);
    } else {
        gram_kernel<<<256, 256, 0, stream>>>(txv, imv, tln, ws, 0);
        dim3 grid(64, 128);
        loss_mfma<<<grid, 256, 0, stream>>>(imq, imv, txk, txv, tln, ws, out);
    }
}

// Round 4
// 1062.504 us; speedup vs baseline: 6.4608x; 1.0567x over previous
//
#include <hip/hip_runtime.h>

#define NIMG 128
#define NTXT 128
#define RDIM 48
#define LWRD 64
#define DDIM 1024
#define LAMB 20.0f
#define FEPS 1e-8f

// ---- ws layout ----
#define WS_INVQ 0
#define WS_VN   6144
#define WS_INVK 12288
#define WS_TVN  20480
#define WS_H    28672        // fp32 H (fallback path)
#define WS_VG   552960       // fp32 Vg (fallback path)
#define WS_MID_BYTES 3391488ull
#define WS_HU   847872       // u32 index: H packed-split, 128*4096
#define WS_VGU  1372160      // u32 index: Vg packed-split, 128*2304
// short indices, chunk-tiled [kc][row][32]:
#define SP_TK   3334144      // per t: hi[32][64][32]=65536 shorts, lo at +65536
#define SP_TV   20111360
#define SP_Q    36888576     // per n: hi[32][48][32]=49152, lo at +49152
#define SP_V    49471488
#define WS_BIG_BYTES 124108800ull

typedef unsigned int u32;
typedef __attribute__((ext_vector_type(8))) short short8;
typedef __attribute__((ext_vector_type(4))) float f32x4;
typedef __attribute__((ext_vector_type(4))) u32 uintx4;
typedef __attribute__((ext_vector_type(2))) u32 uintx2;

#define MFMA(a,b,c) __builtin_amdgcn_mfma_f32_16x16x32_bf16(a,b,c,0,0,0)

__device__ __forceinline__ u32 f2bf(float x){
    u32 u = __float_as_uint(x);
    return (u + 0x7fffu + ((u >> 16) & 1u)) >> 16;
}
__device__ __forceinline__ float bf2f(u32 h){ return __uint_as_float(h << 16); }
__device__ __forceinline__ u32 packsplit(float x){
    u32 h = f2bf(x);
    u32 l = f2bf(x - bf2f(h));
    return h | (l << 16);
}
__device__ __forceinline__ void unpk(uintx4 a, uintx4 b, short8& hi, short8& lo){
    uintx4 h, l;
    h.x = (a.x & 0xffffu) | (a.y << 16);
    h.y = (a.z & 0xffffu) | (a.w << 16);
    h.z = (b.x & 0xffffu) | (b.y << 16);
    h.w = (b.z & 0xffffu) | (b.w << 16);
    l.x = (a.x >> 16) | (a.y & 0xffff0000u);
    l.y = (a.z >> 16) | (a.w & 0xffff0000u);
    l.z = (b.x >> 16) | (b.y & 0xffff0000u);
    l.w = (b.z >> 16) | (b.w & 0xffff0000u);
    hi = __builtin_bit_cast(short8, h);
    lo = __builtin_bit_cast(short8, l);
}

// round-2 fallback staging helpers
#define PSTR  40
#define PTKH  0
#define PTVH  2560
#define PQH   5120
#define PVH   8960
#define LOGAP 12800
__device__ __forceinline__ void split_store(short* stg, int idx, float4 x, float sc){
    float a0 = x.x*sc, a1 = x.y*sc, a2 = x.z*sc, a3 = x.w*sc;
    u32 h0=f2bf(a0), h1=f2bf(a1), h2=f2bf(a2), h3=f2bf(a3);
    u32 l0=f2bf(a0-bf2f(h0)), l1=f2bf(a1-bf2f(h1)), l2=f2bf(a2-bf2f(h2)), l3=f2bf(a3-bf2f(h3));
    uintx2 hv; hv.x = h0 | (h1<<16); hv.y = h2 | (h3<<16);
    uintx2 lv; lv.x = l0 | (l1<<16); lv.y = l2 | (l3<<16);
    *(uintx2*)(stg + idx)         = hv;
    *(uintx2*)(stg + idx + LOGAP) = lv;
}
__device__ __forceinline__ short8 frag_ld(const short* stg, int plane, int rb, int m16, int quad){
    return *(const short8*)(stg + plane + (rb + m16) * PSTR + quad * 8);
}

// ---------------------------------------------------------------------------
__global__ __launch_bounds__(256, 2)
void prep_norms(const float* __restrict__ imq, const float* __restrict__ imv,
                const float* __restrict__ txk, const float* __restrict__ txv,
                float* __restrict__ ws) {
    int vid = blockIdx.x * 4 + (threadIdx.x >> 6);
    int lane = threadIdx.x & 63;
    const float* src;
    if (vid < 6144)       src = imq + (size_t)vid * 1024;
    else if (vid < 12288) src = imv + (size_t)(vid - 6144) * 1024;
    else if (vid < 20480) src = txk + (size_t)(vid - 12288) * 1024;
    else                  src = txv + (size_t)(vid - 20480) * 1024;
    const float4* s4 = (const float4*)src;
    float acc = 0.f;
#pragma unroll
    for (int j = 0; j < 4; ++j) {
        float4 v = s4[lane + 64 * j];
        acc += v.x * v.x + v.y * v.y + v.z * v.z + v.w * v.w;
    }
#pragma unroll
    for (int off = 32; off; off >>= 1) acc += __shfl_down(acc, off, 64);
    if (lane == 0) {
        float nrm = sqrtf(acc);
        if (vid < 6144)       ws[vid] = 1.f / (nrm + FEPS);
        else if (vid < 12288) ws[vid] = nrm;
        else if (vid < 20480) ws[vid] = 1.f / (nrm + FEPS);
        else                  ws[vid] = nrm;
    }
}

// ---------------------------------------------------------------------------
__global__ __launch_bounds__(256, 2)
void split_kernel(const float* __restrict__ imq, const float* __restrict__ imv,
                  const float* __restrict__ txk, const float* __restrict__ txv,
                  const int* __restrict__ tlen, const float* __restrict__ wsf,
                  short* __restrict__ wss) {
    const int ten = blockIdx.y;
    const int jid = blockIdx.x * 256 + threadIdx.x;
    const float* src; float sc; size_t dst; int psz;
    if (ten < 2) {
        int slab = jid >> 13, r = jid & 8191;
        int kc = r >> 8, row = (r >> 2) & 63, ks = r & 3;
        const float* base = (ten == 0) ? txk : txv;
        src = base + (size_t)slab * 65536 + row * 1024 + kc * 32 + ks * 8;
        int nw = tlen[slab];
        if (ten == 0) sc = (row < nw) ? wsf[WS_INVK + slab * 64 + row] : 0.f;
        else          sc = (row < nw) ? 1.f : 0.f;
        dst = (size_t)(ten == 0 ? SP_TK : SP_TV) + (size_t)slab * 131072
            + kc * 2048 + row * 32 + ks * 8;
        psz = 65536;
    } else {
        if (jid >= 786432) return;
        int slab = jid / 6144, r = jid - slab * 6144;
        int kc = r / 192; int rr = r - kc * 192;
        int row = rr >> 2, ks = rr & 3;
        const float* base = (ten == 2) ? imq : imv;
        src = base + (size_t)slab * 49152 + row * 1024 + kc * 32 + ks * 8;
        sc = (ten == 2) ? wsf[WS_INVQ + slab * 48 + row] : 1.f;
        dst = (size_t)(ten == 2 ? SP_Q : SP_V) + (size_t)slab * 98304
            + kc * 1536 + row * 32 + ks * 8;
        psz = 49152;
    }
    float4 x0 = *(const float4*)src;
    float4 x1 = *(const float4*)(src + 4);
    float v[8] = {x0.x, x0.y, x0.z, x0.w, x1.x, x1.y, x1.z, x1.w};
    short8 hv, lv;
#pragma unroll
    for (int i = 0; i < 8; ++i) {
        float a = v[i] * sc;
        u32 h = f2bf(a);
        hv[i] = (short)h;
        lv[i] = (short)f2bf(a - bf2f(h));
    }
    *(short8*)(wss + dst) = hv;
    *(short8*)(wss + dst + psz) = lv;
}

// ---------------------------------------------------------------------------
template <int TS>
__device__ __forceinline__ void gram_body(const float* __restrict__ src,
                                          float* __restrict__ dstf,
                                          u32* __restrict__ dstu,
                                          int mode, int nw, float* sT){
    const int NR = TS * 16;
    int ar = threadIdx.x >> 4, ac = threadIdx.x & 15;
    float acc[TS][TS];
#pragma unroll
    for (int i = 0; i < TS; ++i)
#pragma unroll
        for (int j = 0; j < TS; ++j) acc[i][j] = 0.f;
    for (int kc = 0; kc < 8; ++kc) {
        int k0 = kc * 128;
        for (int jid = threadIdx.x; jid < NR * 32; jid += 256) {
            int row = jid >> 5, c4 = jid & 31;
            float4 x = *(const float4*)(src + row * 1024 + k0 + c4 * 4);
            float sc = (row < nw) ? 1.f : 0.f;
            x.x *= sc; x.y *= sc; x.z *= sc; x.w *= sc;
            *(float4*)&sT[row * 132 + c4 * 4] = x;
        }
        __syncthreads();
#pragma unroll 4
        for (int k4 = 0; k4 < 32; ++k4) {
            float4 av[TS], bv[TS];
#pragma unroll
            for (int i = 0; i < TS; ++i) av[i] = *(const float4*)&sT[(TS*ar + i) * 132 + k4 * 4];
#pragma unroll
            for (int j = 0; j < TS; ++j) bv[j] = *(const float4*)&sT[(TS*ac + j) * 132 + k4 * 4];
#pragma unroll
            for (int i = 0; i < TS; ++i)
#pragma unroll
                for (int j = 0; j < TS; ++j)
                    acc[i][j] += av[i].x*bv[j].x + av[i].y*bv[j].y + av[i].z*bv[j].z + av[i].w*bv[j].w;
        }
        __syncthreads();
    }
#pragma unroll
    for (int i = 0; i < TS; ++i)
#pragma unroll
        for (int j = 0; j < TS; ++j) {
            int idx = (TS*ar + i) * NR + TS*ac + j;
            if (mode) dstu[idx] = packsplit(acc[i][j]);
            else      dstf[idx] = acc[i][j];
        }
}

__global__ __launch_bounds__(256, 2)
void gram_kernel(const float* __restrict__ txv, const float* __restrict__ imv,
                 const int* __restrict__ tlen, float* __restrict__ ws, int mode){
    __shared__ __align__(16) float sT[64 * 132];
    int b = blockIdx.x;
    u32* wsu = (u32*)ws;
    if (b < 128) {
        gram_body<4>(txv + (size_t)b * 65536, ws + WS_H + (size_t)b * 4096,
                     wsu + WS_HU + (size_t)b * 4096, mode, tlen[b], sT);
    } else {
        int n = b - 128;
        gram_body<3>(imv + (size_t)n * 49152, ws + WS_VG + (size_t)n * 2304,
                     wsu + WS_VGU + (size_t)n * 2304, mode, 48, sT);
    }
}

// ---------------------------------------------------------------------------
// Round-4 main kernel: one block = (t, n). 4 waves; wave w owns l-rows
// [16w,16w+16). LDS 40.2 KB -> 4 blocks/CU. B(q,v) staged in LDS (stride 40
// shorts, group-of-8 conflict-clean), A(tk,tv) + H/Vg direct from global.
__global__ __launch_bounds__(256, 4)
void loss_mfma3(const int* __restrict__ tlen, const float* __restrict__ ws,
                float* __restrict__ out) {
    const int n    = blockIdx.x;
    const int t    = blockIdx.y;
    const int tid  = threadIdx.x;
    const int lane = tid & 63;
    const int w    = tid >> 6;       // wave = l-quarter
    const int quad = lane >> 4;
    const int m16  = lane & 15;

    // LDS: 10064 floats = 40,256 B
    __shared__ __align__(16) float Sm[10064];
    u32*   A1w = (u32*)Sm;           // [48][68]
    u32*   A2w = ((u32*)Sm) + 3264;  // [64][52]
    short* stg = (short*)Sm;         // staging: 4 planes x [48][40] = 7680 shorts
    float* P   = Sm + 6592;          // [64][49]
    float* sNl = Sm + 9728;          // 64
    float* sNr = Sm + 9792;          // 48
    float* sD1 = Sm + 9840;          // 48
    float* sS1 = Sm + 9888;          // 48
    float* sD2 = Sm + 9936;          // 64
    float* sS2 = Sm + 10000;         // 64

    const int nw = tlen[t];
    const float nwf = (float)nw;
    const short* wss = (const short*)ws;
    const u32*   wsu = (const u32*)ws;

    // B staging descriptors: 3 x 16B jobs/thread (planes qh,ql,vh,vl)
    const short* bsrc[3]; int bdst[3];
#pragma unroll
    for (int it = 0; it < 3; ++it) {
        int jid = tid + 256 * it;        // 0..767
        int p = jid / 192; int rr = jid - p * 192;
        int row = rr >> 2, ks = rr & 3;
        bsrc[it] = wss + (p < 2 ? SP_Q : SP_V) + (size_t)n * 98304
                 + (size_t)(p & 1) * 49152 + row * 32 + ks * 8;
        bdst[it] = p * 1920 + row * 40 + ks * 8;
    }

    // A-frag global bases (chunk-tiled split planes)
    const short* tkh = wss + SP_TK + (size_t)t * 131072;
    const short* tkl = tkh + 65536;
    const short* tvh = wss + SP_TV + (size_t)t * 131072;
    const short* tvl = tvh + 65536;
    const int ar = (16 * w + m16) * 32 + quad * 8;

    f32x4 accS[3], accG[3];
    f32x4 zf = {0.f, 0.f, 0.f, 0.f};
#pragma unroll
    for (int j = 0; j < 3; ++j) { accS[j] = zf; accG[j] = zf; }

    short8 bj[3];
#pragma unroll
    for (int it = 0; it < 3; ++it) bj[it] = *(const short8*)(bsrc[it]);
    short8 kh0, kl0, th0, tl0, kh1, kl1, th1, tl1;
    kh0 = *(const short8*)(tkh + ar); kl0 = *(const short8*)(tkl + ar);
    th0 = *(const short8*)(tvh + ar); tl0 = *(const short8*)(tvl + ar);

    for (int kc2 = 0; kc2 < 16; ++kc2) {
        const int kc = kc2 * 2;
        // even: consume (kh0..), prefetch kc+1
        {
#pragma unroll
            for (int it = 0; it < 3; ++it) *(short8*)(stg + bdst[it]) = bj[it];
            __syncthreads();
            int bo = (kc + 1) * 1536, ao = (kc + 1) * 2048 + ar;
#pragma unroll
            for (int it = 0; it < 3; ++it) bj[it] = *(const short8*)(bsrc[it] + bo);
            kh1 = *(const short8*)(tkh + ao); kl1 = *(const short8*)(tkl + ao);
            th1 = *(const short8*)(tvh + ao); tl1 = *(const short8*)(tvl + ao);
#pragma unroll
            for (int j = 0; j < 3; ++j) {
                int o = (16 * j + m16) * 40 + quad * 8;
                short8 bqh = *(const short8*)(stg + o);
                short8 bql = *(const short8*)(stg + 1920 + o);
                short8 bvh = *(const short8*)(stg + 3840 + o);
                short8 bvl = *(const short8*)(stg + 5760 + o);
                accS[j] = MFMA(kh0, bqh, accS[j]);
                accS[j] = MFMA(kh0, bql, accS[j]);
                accS[j] = MFMA(kl0, bqh, accS[j]);
                accG[j] = MFMA(th0, bvh, accG[j]);
                accG[j] = MFMA(th0, bvl, accG[j]);
                accG[j] = MFMA(tl0, bvh, accG[j]);
            }
            __syncthreads();
        }
        // odd: consume (kh1..), prefetch kc+2
        {
#pragma unroll
            for (int it = 0; it < 3; ++it) *(short8*)(stg + bdst[it]) = bj[it];
            __syncthreads();
            if (kc2 < 15) {
                int bo = (kc + 2) * 1536, ao = (kc + 2) * 2048 + ar;
#pragma unroll
                for (int it = 0; it < 3; ++it) bj[it] = *(const short8*)(bsrc[it] + bo);
                kh0 = *(const short8*)(tkh + ao); kl0 = *(const short8*)(tkl + ao);
                th0 = *(const short8*)(tvh + ao); tl0 = *(const short8*)(tvl + ao);
            }
#pragma unroll
            for (int j = 0; j < 3; ++j) {
                int o = (16 * j + m16) * 40 + quad * 8;
                short8 bqh = *(const short8*)(stg + o);
                short8 bql = *(const short8*)(stg + 1920 + o);
                short8 bvh = *(const short8*)(stg + 3840 + o);
                short8 bvl = *(const short8*)(stg + 5760 + o);
                accS[j] = MFMA(kh1, bqh, accS[j]);
                accS[j] = MFMA(kh1, bql, accS[j]);
                accS[j] = MFMA(kl1, bqh, accS[j]);
                accG[j] = MFMA(th1, bvh, accG[j]);
                accG[j] = MFMA(th1, bvl, accG[j]);
                accG[j] = MFMA(tl1, bvh, accG[j]);
            }
            __syncthreads();
        }
    }

    // ---- P = leaky_relu(S); lane holds S[l=16w+4q+v][r=16j+m16] ----
#pragma unroll
    for (int j = 0; j < 3; ++j)
#pragma unroll
        for (int v = 0; v < 4; ++v) {
            int l = 16 * w + quad * 4 + v;
            float x = accS[j][v];
            P[l * 49 + 16 * j + m16] = (x > 0.f) ? x : 0.1f * x;
        }
    __syncthreads();

    // ---- norms + zero d1/s1 accumulators ----
    if (tid < 64) {
        float s = 0.f;
#pragma unroll 4
        for (int r = 0; r < 48; ++r) { float x = P[tid * 49 + r]; s += x * x; }
        sNl[tid] = sqrtf(s) + FEPS;
    } else if (tid < 112) {
        int r = tid - 64;
        float s = 0.f;
#pragma unroll 4
        for (int l = 0; l < 64; ++l) { float x = P[l * 49 + r]; s += x * x; }
        sNr[r] = sqrtf(s) + FEPS;
    } else if (tid < 208) {
        int k = tid - 112;
        if (k < 48) sD1[k] = 0.f; else sS1[k - 48] = 0.f;
    }
    __syncthreads();

    // ---- softmax + focal (tids 0..63: t2i rows -> A2; 64..111: i2t -> A1) ----
    if (tid < 64) {
        int l = tid;
        u32* row = A2w + l * 52;
        if (l < nw) {
            float a[48]; float mx = -1e30f;
            const float* Pr = P + l * 49;
#pragma unroll
            for (int r = 0; r < 48; ++r) {
                float x = LAMB * Pr[r] / sNr[r];
                a[r] = x; mx = fmaxf(mx, x);
            }
            float se = 0.f;
#pragma unroll
            for (int r = 0; r < 48; ++r) { float e = __expf(a[r] - mx); a[r] = e; se += e; }
            float suma = 0.f;
#pragma unroll
            for (int r = 0; r < 48; ++r) { float x = a[r] / se; a[r] = x; suma += x; }
            float s2 = 0.f;
#pragma unroll
            for (int r = 0; r < 48; ++r) if (a[r] * 48.f - suma > 0.f) s2 += a[r];
            float ri = (s2 > 0.f) ? 1.f / s2 : 1.f;
#pragma unroll
            for (int r = 0; r < 48; ++r) {
                float x = (a[r] * 48.f - suma > 0.f) ? a[r] * ri : 0.f;
                row[r] = packsplit(x);
            }
        } else {
#pragma unroll
            for (int r = 0; r < 48; ++r) row[r] = 0u;
        }
    } else if (tid < 112) {
        int r = tid - 64;
        float a[64]; float mx = -1e30f;
#pragma unroll
        for (int l = 0; l < 64; ++l) {
            float x = (l < nw) ? (LAMB * P[l * 49 + r] / sNl[l]) : -1e30f;
            a[l] = x; mx = fmaxf(mx, x);
        }
        float se = 0.f;
#pragma unroll
        for (int l = 0; l < 64; ++l) { float e = __expf(a[l] - mx); a[l] = e; se += e; }
        float suma = 0.f;
#pragma unroll
        for (int l = 0; l < 64; ++l) { float x = a[l] / se; a[l] = x; suma += x; }
        float s2 = 0.f;
#pragma unroll
        for (int l = 0; l < 64; ++l) if (a[l] * nwf - suma > 0.f) s2 += a[l];
        float ri = (s2 > 0.f) ? 1.f / s2 : 1.f;
        u32* row = A1w + r * 68;
#pragma unroll
        for (int l = 0; l < 64; ++l) {
            float x = (a[l] * nwf - suma > 0.f) ? a[l] * ri : 0.f;
            row[l] = packsplit(x);
        }
    }
    __syncthreads();

    // ---- Y = H @ A1^T (H direct global); accY[j] holds Y[l][r=16j+m16] ----
    f32x4 accY[3];
#pragma unroll
    for (int j = 0; j < 3; ++j) accY[j] = zf;
    const u32* Hg = wsu + WS_HU + (size_t)t * 4096 + (16 * w + m16) * 64;
#pragma unroll
    for (int ks = 0; ks < 2; ++ks) {
        int kb = ks * 32 + quad * 8;
        short8 Ah, Al;
        {
            uintx4 wa = *(const uintx4*)&Hg[kb];
            uintx4 wb = *(const uintx4*)&Hg[kb + 4];
            unpk(wa, wb, Ah, Al);
        }
#pragma unroll
        for (int j = 0; j < 3; ++j) {
            int base = (16 * j + m16) * 68 + kb;
            uintx4 wa = *(const uintx4*)&A1w[base];
            uintx4 wb = *(const uintx4*)&A1w[base + 4];
            short8 Bh, Bl;
            unpk(wa, wb, Bh, Bl);
            accY[j] = MFMA(Ah, Bh, accY[j]);
            accY[j] = MFMA(Ah, Bl, accY[j]);
            accY[j] = MFMA(Al, Bh, accY[j]);
        }
    }
    {
        float td[3] = {0.f, 0.f, 0.f}, ts[3] = {0.f, 0.f, 0.f};
#pragma unroll
        for (int v = 0; v < 4; ++v) {
            int l = 16 * w + quad * 4 + v;
#pragma unroll
            for (int j = 0; j < 3; ++j) {
                u32 wv = A1w[(16 * j + m16) * 68 + l];
                float av = bf2f(wv & 0xffffu) + bf2f(wv >> 16);
                td[j] += av * accG[j][v];
                ts[j] += av * accY[j][v];
            }
        }
#pragma unroll
        for (int j = 0; j < 3; ++j) {
            float d = td[j]; d += __shfl_xor(d, 16, 64); d += __shfl_xor(d, 32, 64);
            float s = ts[j]; s += __shfl_xor(s, 16, 64); s += __shfl_xor(s, 32, 64);
            if (quad == 0) {
                atomicAdd(&sD1[16 * j + m16], d);
                atomicAdd(&sS1[16 * j + m16], s);
            }
        }
    }

    // ---- Y2 = Vg @ A2^T (Vg direct global); accY2[i] = Y2[r=16i+..][l=16w+m16]
    f32x4 accY2[3];
#pragma unroll
    for (int i = 0; i < 3; ++i) accY2[i] = zf;
    const u32* Vgg = wsu + WS_VGU + (size_t)n * 2304;
#pragma unroll
    for (int ks = 0; ks < 2; ++ks) {
        const bool dead = (ks == 1) && (quad >= 2);
        const int kb = (ks == 0) ? quad * 8 : 32 + (quad & 1) * 8;
        short8 Bh2, Bl2;
        {
            uintx4 wa = {0,0,0,0}, wb = {0,0,0,0};
            if (!dead) {
                int base = (16 * w + m16) * 52 + kb;
                wa = *(const uintx4*)&A2w[base];
                wb = *(const uintx4*)&A2w[base + 4];
            }
            unpk(wa, wb, Bh2, Bl2);
        }
#pragma unroll
        for (int i = 0; i < 3; ++i) {
            uintx4 wa = {0,0,0,0}, wb = {0,0,0,0};
            if (!dead) {
                wa = *(const uintx4*)&Vgg[(16 * i + m16) * 48 + kb];
                wb = *(const uintx4*)&Vgg[(16 * i + m16) * 48 + kb + 4];
            }
            short8 Ah2, Al2;
            unpk(wa, wb, Ah2, Al2);
            accY2[i] = MFMA(Ah2, Bh2, accY2[i]);
            accY2[i] = MFMA(Ah2, Bl2, accY2[i]);
            accY2[i] = MFMA(Al2, Bh2, accY2[i]);
        }
    }
    {
        // s2[l=16w+m16] = sum_r A2[l,r]*Y2[r,l]
        float u = 0.f;
#pragma unroll
        for (int i = 0; i < 3; ++i)
#pragma unroll
            for (int v = 0; v < 4; ++v) {
                int r = 16 * i + quad * 4 + v;
                u32 wv = A2w[(16 * w + m16) * 52 + r];
                float av = bf2f(wv & 0xffffu) + bf2f(wv >> 16);
                u += av * accY2[i][v];
            }
        u += __shfl_xor(u, 16, 64); u += __shfl_xor(u, 32, 64);
        if (quad == 0) sS2[16 * w + m16] = u;
        // d2[l=16w+4q+v] = sum_r A2[l,r]*G[l,r]
        float ud[4] = {0.f, 0.f, 0.f, 0.f};
#pragma unroll
        for (int v = 0; v < 4; ++v) {
            int l = 16 * w + quad * 4 + v;
#pragma unroll
            for (int j = 0; j < 3; ++j) {
                u32 wv = A2w[l * 52 + 16 * j + m16];
                float av = bf2f(wv & 0xffffu) + bf2f(wv >> 16);
                ud[v] += av * accG[j][v];
            }
        }
#pragma unroll
        for (int v = 0; v < 4; ++v) {
            float d = ud[v];
            d += __shfl_xor(d, 1, 64); d += __shfl_xor(d, 2, 64);
            d += __shfl_xor(d, 4, 64); d += __shfl_xor(d, 8, 64);
            if (m16 == 0) sD2[16 * w + quad * 4 + v] = d;
        }
    }
    __syncthreads();

    // ---- cosine epilogue (reference eps semantics) ----
    if (tid < 48) {
        int r = tid;
        float wn = sqrtf(sS1[r]);
        float dh = sD1[r] / (wn + FEPS);
        float nh = wn / (wn + FEPS);
        float vn = ws[WS_VN + n * 48 + r];
        sD1[r] = dh / fmaxf(vn * nh, FEPS);
    } else if (tid >= 64 && tid < 128) {
        int l = tid - 64;
        if (l < nw) {
            float wn = sqrtf(sS2[l]);
            float dh = sD2[l] / (wn + FEPS);
            float nh = wn / (wn + FEPS);
            float tn = ws[WS_TVN + t * 64 + l];
            sD2[l] = dh / fmaxf(tn * nh, FEPS);
        }
    }
    __syncthreads();
    if (tid == 0) {
        float s = 0.f;
        for (int r = 0; r < 48; ++r) s += sD1[r];
        out[(size_t)n * NTXT + t] = s / 48.f;
    } else if (tid == 64) {
        float s = 0.f;
        for (int l = 0; l < nw; ++l) s += sD2[l];
        out[(size_t)(NIMG * NTXT) + (size_t)n * NTXT + t] = s / nwf;
    }
}

// ---------------------------------------------------------------------------
// Round-2 verified fallback (only if ws too small for split planes).
__global__ __launch_bounds__(256, 2)
void loss_mfma(const float* __restrict__ imq, const float* __restrict__ imv,
               const float* __restrict__ txk, const float* __restrict__ txv,
               const int* __restrict__ tlen, const float* __restrict__ ws,
               float* __restrict__ out) {
    const int npair = blockIdx.x;
    const int t     = blockIdx.y;
    const int n0    = npair * 2;
    const int tid   = threadIdx.x;
    const int lane  = tid & 63;
    const int w     = tid >> 6;
    const int nl    = w >> 1;
    const int hh    = w & 1;
    const int quad  = lane >> 4;
    const int m16   = lane & 15;

    __shared__ __align__(16) float Sm[19904];
    short* stage = (short*)Sm;
    u32*   A1w   = (u32*)Sm;
    u32*   A2w   = ((u32*)Sm) + 6528;
    float* P     = Sm + 12800;
    u32*   HVw   = (u32*)(Sm + 12800);
    float* sInvK = Sm + 19072;
    float* sInvQ = sInvK + 64;
    float* sNl   = sInvQ + 96;
    float* sNr   = sNl + 128;
    float* sD1   = sNr + 96;
    float* sS1   = sD1 + 96;
    float* sD2   = sS1 + 96;
    float* sS2   = sD2 + 128;

    const int nw = tlen[t];
    const float nwf = (float)nw;
    if (tid < 64) sInvK[tid] = ws[WS_INVK + t * 64 + tid];
    else if (tid < 160) {
        int i = tid - 64; int nn = i >= 48; int r = i - 48 * nn;
        sInvQ[i] = ws[WS_INVQ + (n0 + nn) * 48 + r];
    }
    __syncthreads();

    const float* tkb = txk + (size_t)t * 65536;
    const float* tvb = txv + (size_t)t * 65536;
    const float* qb0 = imq + (size_t)n0 * 49152;
    const float* vb0 = imv + (size_t)n0 * 49152;

    const float* sp[10]; int di[10]; float scl[10];
#pragma unroll
    for (int it = 0; it < 10; ++it) {
        int jid = tid + 256 * it;
        const float* s; int plane; int row, c4; float sc;
        if (it < 2) {
            row = jid >> 3; c4 = jid & 7;
            s = tkb + row * 1024 + c4 * 4;
            sc = (row < nw) ? sInvK[row] : 0.f;
            plane = PTKH;
        } else if (it < 4) {
            int j2 = jid - 512; row = j2 >> 3; c4 = j2 & 7;
            s = tvb + row * 1024 + c4 * 4;
            sc = (row < nw) ? 1.f : 0.f;
            plane = PTVH;
        } else if (it < 7) {
            int j2 = jid - 1024; row = j2 >> 3; c4 = j2 & 7;
            s = qb0 + row * 1024 + c4 * 4;
            sc = sInvQ[row];
            plane = PQH;
        } else {
            int j2 = jid - 1792; row = j2 >> 3; c4 = j2 & 7;
            s = vb0 + row * 1024 + c4 * 4;
            sc = 1.f;
            plane = PVH;
        }
        sp[it] = s; di[it] = plane + row * PSTR + c4 * 4; scl[it] = sc;
    }

    f32x4 accS[2][3], accG[2][3];
    f32x4 zf = {0.f, 0.f, 0.f, 0.f};
#pragma unroll
    for (int i = 0; i < 2; ++i)
#pragma unroll
        for (int j = 0; j < 3; ++j) { accS[i][j] = zf; accG[i][j] = zf; }

    float4 pf[10];
#pragma unroll
    for (int it = 0; it < 10; ++it) pf[it] = *(const float4*)(sp[it]);

    for (int kc = 0; kc < 32; ++kc) {
#pragma unroll
        for (int it = 0; it < 10; ++it) split_store(stage, di[it], pf[it], scl[it]);
        __syncthreads();
        if (kc < 31) {
            const int ko = (kc + 1) * 32;
#pragma unroll
            for (int it = 0; it < 10; ++it) pf[it] = *(const float4*)(sp[it] + ko);
        }
        short8 akh[2], akl[2], ath[2], atl[2];
#pragma unroll
        for (int i = 0; i < 2; ++i) {
            int rb = 32 * hh + 16 * i;
            akh[i] = frag_ld(stage, PTKH,         rb, m16, quad);
            akl[i] = frag_ld(stage, PTKH + LOGAP, rb, m16, quad);
            ath[i] = frag_ld(stage, PTVH,         rb, m16, quad);
            atl[i] = frag_ld(stage, PTVH + LOGAP, rb, m16, quad);
        }
        short8 bqh[3], bql[3], bvh[3], bvl[3];
#pragma unroll
        for (int j = 0; j < 3; ++j) {
            int rb = nl * 48 + 16 * j;
            bqh[j] = frag_ld(stage, PQH,         rb, m16, quad);
            bql[j] = frag_ld(stage, PQH + LOGAP, rb, m16, quad);
            bvh[j] = frag_ld(stage, PVH,         rb, m16, quad);
            bvl[j] = frag_ld(stage, PVH + LOGAP, rb, m16, quad);
        }
#pragma unroll
        for (int i = 0; i < 2; ++i)
#pragma unroll
            for (int j = 0; j < 3; ++j) {
                accS[i][j] = MFMA(akh[i], bqh[j], accS[i][j]);
                accS[i][j] = MFMA(akh[i], bql[j], accS[i][j]);
                accS[i][j] = MFMA(akl[i], bqh[j], accS[i][j]);
                accG[i][j] = MFMA(ath[i], bvh[j], accG[i][j]);
                accG[i][j] = MFMA(ath[i], bvl[j], accG[i][j]);
                accG[i][j] = MFMA(atl[i], bvh[j], accG[i][j]);
            }
        __syncthreads();
    }

#pragma unroll
    for (int i = 0; i < 2; ++i)
#pragma unroll
        for (int j = 0; j < 3; ++j)
#pragma unroll
            for (int v = 0; v < 4; ++v) {
                int l = 32 * hh + 16 * i + quad * 4 + v;
                int r = 16 * j + m16;
                float x = accS[i][j][v];
                P[nl * 3136 + l * 49 + r] = (x > 0.f) ? x : 0.1f * x;
            }
    __syncthreads();

    if (tid < 128) {
        int n = tid >> 6, l = tid & 63;
        float s = 0.f;
#pragma unroll 4
        for (int r = 0; r < 48; ++r) { float x = P[n*3136 + l*49 + r]; s += x * x; }
        sNl[n * 64 + l] = sqrtf(s) + FEPS;
    } else if (tid < 224) {
        int i = tid - 128; int n = i >= 48; int r = i - 48 * n;
        float s = 0.f;
#pragma unroll 4
        for (int l = 0; l < 64; ++l) { float x = P[n*3136 + l*49 + r]; s += x * x; }
        sNr[n * 48 + r] = sqrtf(s) + FEPS;
    } else {
        for (int k = tid - 224; k < 448; k += 32) sD1[k] = 0.f;
    }
    __syncthreads();

    if (tid < 128) {
        int n = tid >> 6, l = tid & 63;
        u32* row = A2w + n * 3072 + l * 48;
        if (l < nw) {
            float a[48]; float mx = -1e30f;
            const float* Pr = P + n * 3136 + l * 49;
#pragma unroll
            for (int r = 0; r < 48; ++r) {
                float x = LAMB * Pr[r] / sNr[n * 48 + r];
                a[r] = x; mx = fmaxf(mx, x);
            }
            float se = 0.f;
#pragma unroll
            for (int r = 0; r < 48; ++r) { float e = __expf(a[r] - mx); a[r] = e; se += e; }
            float suma = 0.f;
#pragma unroll
            for (int r = 0; r < 48; ++r) { float x = a[r] / se; a[r] = x; suma += x; }
            float s2 = 0.f;
#pragma unroll
            for (int r = 0; r < 48; ++r) if (a[r] * 48.f - suma > 0.f) s2 += a[r];
            float ri = (s2 > 0.f) ? 1.f / s2 : 1.f;
#pragma unroll
            for (int r = 0; r < 48; ++r) {
                float x = (a[r] * 48.f - suma > 0.f) ? a[r] * ri : 0.f;
                row[r] = packsplit(x);
            }
        } else {
#pragma unroll
            for (int r = 0; r < 48; ++r) row[r] = 0u;
        }
    } else if (tid < 224) {
        int i = tid - 128; int n = i >= 48; int r = i - 48 * n;
        float a[64]; float mx = -1e30f;
#pragma unroll
        for (int l = 0; l < 64; ++l) {
            float x = (l < nw) ? (LAMB * P[n*3136 + l*49 + r] / sNl[n * 64 + l]) : -1e30f;
            a[l] = x; mx = fmaxf(mx, x);
        }
        float se = 0.f;
#pragma unroll
        for (int l = 0; l < 64; ++l) { float e = __expf(a[l] - mx); a[l] = e; se += e; }
        float suma = 0.f;
#pragma unroll
        for (int l = 0; l < 64; ++l) { float x = a[l] / se; a[l] = x; suma += x; }
        float s2 = 0.f;
#pragma unroll
        for (int l = 0; l < 64; ++l) if (a[l] * nwf - suma > 0.f) s2 += a[l];
        float ri = (s2 > 0.f) ? 1.f / s2 : 1.f;
        u32* row = A1w + n * 3264 + r * 68;
#pragma unroll
        for (int l = 0; l < 64; ++l) {
            float x = (a[l] * nwf - suma > 0.f) ? a[l] * ri : 0.f;
            row[l] = packsplit(x);
        }
    }
    __syncthreads();

    {
        const float* Hg = ws + WS_H + (size_t)t * 4096;
        for (int jid = tid; jid < 1024; jid += 256) {
            int row = jid >> 4, c4 = jid & 15;
            float4 x = *(const float4*)(Hg + row * 64 + c4 * 4);
            uintx4 p; p.x = packsplit(x.x); p.y = packsplit(x.y);
            p.z = packsplit(x.z); p.w = packsplit(x.w);
            *(uintx4*)&HVw[row * 68 + c4 * 4] = p;
        }
    }
    __syncthreads();

    f32x4 accY[2][3];
#pragma unroll
    for (int i = 0; i < 2; ++i)
#pragma unroll
        for (int j = 0; j < 3; ++j) accY[i][j] = zf;
#pragma unroll
    for (int ks = 0; ks < 2; ++ks) {
        int kb = ks * 32 + quad * 8;
        short8 Ah[2], Al[2];
#pragma unroll
        for (int i = 0; i < 2; ++i) {
            int row = 32 * hh + 16 * i + m16;
            uintx4 wa = *(const uintx4*)&HVw[row * 68 + kb];
            uintx4 wb = *(const uintx4*)&HVw[row * 68 + kb + 4];
            unpk(wa, wb, Ah[i], Al[i]);
        }
        short8 Bh[3], Bl[3];
#pragma unroll
        for (int j = 0; j < 3; ++j) {
            int base = nl * 3264 + (16 * j + m16) * 68 + kb;
            uintx4 wa = *(const uintx4*)&A1w[base];
            uintx4 wb = *(const uintx4*)&A1w[base + 4];
            unpk(wa, wb, Bh[j], Bl[j]);
        }
#pragma unroll
        for (int i = 0; i < 2; ++i)
#pragma unroll
            for (int j = 0; j < 3; ++j) {
                accY[i][j] = MFMA(Ah[i], Bh[j], accY[i][j]);
                accY[i][j] = MFMA(Ah[i], Bl[j], accY[i][j]);
                accY[i][j] = MFMA(Al[i], Bh[j], accY[i][j]);
            }
    }
    {
        float td[3] = {0.f, 0.f, 0.f}, ts[3] = {0.f, 0.f, 0.f};
#pragma unroll
        for (int i = 0; i < 2; ++i)
#pragma unroll
            for (int v = 0; v < 4; ++v) {
                int l = 32 * hh + 16 * i + quad * 4 + v;
#pragma unroll
                for (int j = 0; j < 3; ++j) {
                    u32 wv = A1w[nl * 3264 + (16 * j + m16) * 68 + l];
                    float av = bf2f(wv & 0xffffu) + bf2f(wv >> 16);
                    td[j] += av * accG[i][j][v];
                    ts[j] += av * accY[i][j][v];
                }
            }
#pragma unroll
        for (int j = 0; j < 3; ++j) {
            float d = td[j]; d += __shfl_xor(d, 16, 64); d += __shfl_xor(d, 32, 64);
            float s = ts[j]; s += __shfl_xor(s, 16, 64); s += __shfl_xor(s, 32, 64);
            if (quad == 0) {
                atomicAdd(&sD1[nl * 48 + 16 * j + m16], d);
                atomicAdd(&sS1[nl * 48 + 16 * j + m16], s);
            }
        }
    }
    __syncthreads();

    {
        const float* Vgg = ws + WS_VG + (size_t)n0 * 2304;
        for (int jid = tid; jid < 1152; jid += 256) {
            int nn = jid >= 576; int j2 = jid - 576 * nn;
            int row = j2 / 12, c4 = j2 % 12;
            float4 x = *(const float4*)(Vgg + nn * 2304 + row * 48 + c4 * 4);
            uintx4 p; p.x = packsplit(x.x); p.y = packsplit(x.y);
            p.z = packsplit(x.z); p.w = packsplit(x.w);
            *(uintx4*)&HVw[nn * 2496 + row * 52 + c4 * 4] = p;
        }
    }
    __syncthreads();

    f32x4 accY2[3][2];
#pragma unroll
    for (int i = 0; i < 3; ++i)
#pragma unroll
        for (int j = 0; j < 2; ++j) accY2[i][j] = zf;
    const u32* VgW = HVw + nl * 2496;
#pragma unroll
    for (int ks = 0; ks < 2; ++ks) {
        const bool dead = (ks == 1) && (quad >= 2);
        const int kb = (ks == 0) ? quad * 8 : 32 + (quad & 1) * 8;
        short8 Ah2[3], Al2[3];
#pragma unroll
        for (int i = 0; i < 3; ++i) {
            uintx4 wa = {0,0,0,0}, wb = {0,0,0,0};
            if (!dead) {
                int row = 16 * i + m16;
                wa = *(const uintx4*)&VgW[row * 52 + kb];
                wb = *(const uintx4*)&VgW[row * 52 + kb + 4];
            }
            unpk(wa, wb, Ah2[i], Al2[i]);
        }
        short8 Bh2[2], Bl2[2];
#pragma unroll
        for (int j = 0; j < 2; ++j) {
            uintx4 wa = {0,0,0,0}, wb = {0,0,0,0};
            if (!dead) {
                int l = 32 * hh + 16 * j + m16;
                wa = *(const uintx4*)&A2w[nl * 3072 + l * 48 + kb];
                wb = *(const uintx4*)&A2w[nl * 3072 + l * 48 + kb + 4];
            }
            unpk(wa, wb, Bh2[j], Bl2[j]);
        }
#pragma unroll
        for (int i = 0; i < 3; ++i)
#pragma unroll
            for (int j = 0; j < 2; ++j) {
                accY2[i][j] = MFMA(Ah2[i], Bh2[j], accY2[i][j]);
                accY2[i][j] = MFMA(Ah2[i], Bl2[j], accY2[i][j]);
                accY2[i][j] = MFMA(Al2[i], Bh2[j], accY2[i][j]);
            }
    }
    {
        float u[2] = {0.f, 0.f};
#pragma unroll
        for (int i = 0; i < 3; ++i)
#pragma unroll
            for (int v = 0; v < 4; ++v) {
                int r = 16 * i + quad * 4 + v;
#pragma unroll
                for (int j = 0; j < 2; ++j) {
                    int l = 32 * hh + 16 * j + m16;
                    u32 wv = A2w[nl * 3072 + l * 48 + r];
                    float av = bf2f(wv & 0xffffu) + bf2f(wv >> 16);
                    u[j] += av * accY2[i][j][v];
                }
            }
#pragma unroll
        for (int j = 0; j < 2; ++j) {
            float s = u[j]; s += __shfl_xor(s, 16, 64); s += __shfl_xor(s, 32, 64);
            if (quad == 0) sS2[nl * 64 + 32 * hh + 16 * j + m16] = s;
        }
        float ud[2][4];
#pragma unroll
        for (int i = 0; i < 2; ++i)
#pragma unroll
            for (int v = 0; v < 4; ++v) ud[i][v] = 0.f;
#pragma unroll
        for (int i = 0; i < 2; ++i)
#pragma unroll
            for (int v = 0; v < 4; ++v) {
                int l = 32 * hh + 16 * i + quad * 4 + v;
#pragma unroll
                for (int j = 0; j < 3; ++j) {
                    u32 wv = A2w[nl * 3072 + l * 48 + (16 * j + m16)];
                    float av = bf2f(wv & 0xffffu) + bf2f(wv >> 16);
                    ud[i][v] += av * accG[i][j][v];
                }
            }
#pragma unroll
        for (int i = 0; i < 2; ++i)
#pragma unroll
            for (int v = 0; v < 4; ++v) {
                float d = ud[i][v];
                d += __shfl_xor(d, 1, 64); d += __shfl_xor(d, 2, 64);
                d += __shfl_xor(d, 4, 64); d += __shfl_xor(d, 8, 64);
                if (m16 == 0) sD2[nl * 64 + 32 * hh + 16 * i + quad * 4 + v] = d;
            }
    }
    __syncthreads();

    if (tid < 96) {
        int n = tid >= 48; int r = tid - 48 * n;
        float wn = sqrtf(sS1[n * 48 + r]);
        float dh = sD1[n * 48 + r] / (wn + FEPS);
        float nh = wn / (wn + FEPS);
        float vn = ws[WS_VN + (n0 + n) * 48 + r];
        sD1[n * 48 + r] = dh / fmaxf(vn * nh, FEPS);
    } else if (tid >= 128) {
        int i = tid - 128; int n = i >> 6, l = i & 63;
        if (l < nw) {
            float wn = sqrtf(sS2[n * 64 + l]);
            float dh = sD2[n * 64 + l] / (wn + FEPS);
            float nh = wn / (wn + FEPS);
            float tn = ws[WS_TVN + t * 64 + l];
            sD2[n * 64 + l] = dh / fmaxf(tn * nh, FEPS);
        }
    }
    __syncthreads();
    if (tid < 2) {
        float s = 0.f;
        for (int r = 0; r < 48; ++r) s += sD1[tid * 48 + r];
        out[(size_t)(n0 + tid) * NTXT + t] = s / 48.f;
    } else if (tid == 64 || tid == 65) {
        int n = tid - 64;
        float s = 0.f;
        for (int l = 0; l < nw; ++l) s += sD2[n * 64 + l];
        out[(size_t)(NIMG * NTXT) + (size_t)(n0 + n) * NTXT + t] = s / nwf;
    }
}

extern "C" void kernel_launch(void* const* d_in, const int* in_sizes, int n_in,
                              void* d_out, int out_size, void* d_ws, size_t ws_size,
                              hipStream_t stream) {
    (void)in_sizes; (void)n_in; (void)out_size;
    const float* imq = (const float*)d_in[0];
    const float* imv = (const float*)d_in[1];
    const float* txk = (const float*)d_in[2];
    const float* txv = (const float*)d_in[3];
    const int*   tln = (const int*)d_in[4];
    float* out = (float*)d_out;
    float* ws  = (float*)d_ws;

    prep_norms<<<7168, 256, 0, stream>>>(imq, imv, txk, txv, ws);
    if (ws_size >= WS_BIG_BYTES) {
        split_kernel<<<dim3(4096, 4), 256, 0, stream>>>(imq, imv, txk, txv, tln,
                                                        ws, (short*)d_ws);
        gram_kernel<<<256, 256, 0, stream>>>(txv, imv, tln, ws, 1);
        dim3 grid(NIMG, NTXT);
        loss_mfma3<<<grid, 256, 0, stream>>>(tln, ws, out);
    } else {
        gram_kernel<<<256, 256, 0, stream>>>(txv, imv, tln, ws, 0);
        dim3 grid(64, 128);
        loss_mfma<<<grid, 256, 0, stream>>>(imq, imv, txk, txv, tln, ws, out);
    }
}